// Round 1
// baseline (2010.504 us; speedup 1.0000x reference)
//
#include <hip/hip_runtime.h>

#define TPB 256
constexpr float BN_EPS = 1e-5f;

__device__ __forceinline__ float sigmoidf_(float x) { return 1.f / (1.f + __expf(-x)); }

// ---------- build x = [sparse_embed (20*8) | dense (64)] : (B, 224) ----------
__global__ __launch_bounds__(TPB) void build_x_kernel(
    const int* __restrict__ Xs, const float* __restrict__ Xd,
    const float* __restrict__ emb, float* __restrict__ x, int B)
{
    int idx = blockIdx.x * TPB + threadIdx.x;
    if (idx >= B * 224) return;
    int b = idx / 224, c = idx - b * 224;
    float v;
    if (c < 160) {
        int s = c >> 3, j = c & 7;
        int e = Xs[b * 20 + s];
        v = emb[((size_t)s * 1000 + e) * 8 + j];
    } else {
        v = Xd[b * 64 + (c - 160)];
    }
    x[idx] = v;
}

// ---------- tiled fp32 GEMM: C(M,N) = A(M,K) @ W(N,K)^T (+bias)(+bn+relu) ----------
template<bool BNRELU>
__global__ __launch_bounds__(256) void gemm_nt(
    const float* __restrict__ A, const float* __restrict__ W,
    const float* __restrict__ bias,
    const float* __restrict__ g, const float* __restrict__ bb,
    const float* __restrict__ bm, const float* __restrict__ bv,
    float* __restrict__ C, int M, int N, int K)
{
    constexpr int SL = 68;   // padded row stride: 68*4B = 272B, 16B aligned, bank-stride 4
    __shared__ float As[32 * SL];
    __shared__ float Ws[32 * SL];
    int tid = threadIdx.x;
    int m0 = blockIdx.x * 64, n0 = blockIdx.y * 64;
    int tm = (tid & 15) * 4, tn = (tid >> 4) * 4;
    float acc[4][4] = {};
    for (int k0 = 0; k0 < K; k0 += 32) {
#pragma unroll
        for (int i = 0; i < 2; ++i) {
            int idx = tid + i * 256;          // 0..511 -> 64 rows x 8 float4
            int r = idx >> 3, kv = idx & 7;
            int kk = kv * 4;
            float4 av = make_float4(0.f, 0.f, 0.f, 0.f);
            int gm = m0 + r;
            if (gm < M) av = *(const float4*)(A + (size_t)gm * K + k0 + kk);
            As[(kk + 0) * SL + r] = av.x; As[(kk + 1) * SL + r] = av.y;
            As[(kk + 2) * SL + r] = av.z; As[(kk + 3) * SL + r] = av.w;
            float4 wv = make_float4(0.f, 0.f, 0.f, 0.f);
            int gn = n0 + r;
            if (gn < N) wv = *(const float4*)(W + (size_t)gn * K + k0 + kk);
            Ws[(kk + 0) * SL + r] = wv.x; Ws[(kk + 1) * SL + r] = wv.y;
            Ws[(kk + 2) * SL + r] = wv.z; Ws[(kk + 3) * SL + r] = wv.w;
        }
        __syncthreads();
#pragma unroll
        for (int k = 0; k < 32; ++k) {
            float4 a = *(const float4*)&As[k * SL + tm];
            float4 b = *(const float4*)&Ws[k * SL + tn];
            acc[0][0] += a.x * b.x; acc[0][1] += a.x * b.y; acc[0][2] += a.x * b.z; acc[0][3] += a.x * b.w;
            acc[1][0] += a.y * b.x; acc[1][1] += a.y * b.y; acc[1][2] += a.y * b.z; acc[1][3] += a.y * b.w;
            acc[2][0] += a.z * b.x; acc[2][1] += a.z * b.y; acc[2][2] += a.z * b.z; acc[2][3] += a.z * b.w;
            acc[3][0] += a.w * b.x; acc[3][1] += a.w * b.y; acc[3][2] += a.w * b.z; acc[3][3] += a.w * b.w;
        }
        __syncthreads();
    }
#pragma unroll
    for (int i = 0; i < 4; ++i) {
        int gm = m0 + tm + i;
        if (gm >= M) continue;
#pragma unroll
        for (int j = 0; j < 4; ++j) {
            int gn = n0 + tn + j;
            if (gn >= N) continue;
            float t = acc[i][j];
            if (bias) t += bias[gn];
            if (BNRELU) {
                float sc = g[gn] * rsqrtf(bv[gn] + BN_EPS);
                t = t * sc + (bb[gn] - bm[gn] * sc);
                t = fmaxf(t, 0.f);
            }
            C[(size_t)gm * N + gn] = t;
        }
    }
}

// ---------- C(M,8) = A(M,K) @ W(8,K)^T + bias ----------
__global__ __launch_bounds__(TPB) void gemm_n8(
    const float* __restrict__ A, const float* __restrict__ Wt,
    const float* __restrict__ bias, float* __restrict__ C, int M, int K)
{
    int idx = blockIdx.x * TPB + threadIdx.x;
    if (idx >= M * 8) return;
    int r = idx >> 3, j = idx & 7;
    const float4* a4 = (const float4*)(A + (size_t)r * K);
    const float4* w4 = (const float4*)(Wt + (size_t)j * K);
    float s = 0.f;
    int k4 = K >> 2;
    for (int k = 0; k < k4; ++k) {
        float4 av = a4[k], wv = w4[k];
        s += av.x * wv.x + av.y * wv.y + av.z * wv.z + av.w * wv.w;
    }
    if (bias) s += bias[j];
    C[idx] = s;
}

// ---------- per-node attention coefficients: el/er (N, HN) ----------
template<int HN, int DHD>
__global__ __launch_bounds__(TPB) void attn_coef_kernel(
    const float* __restrict__ feat, const float* __restrict__ al,
    const float* __restrict__ ar, float* __restrict__ el, float* __restrict__ er, int Nn)
{
    int idx = blockIdx.x * TPB + threadIdx.x;
    if (idx >= Nn * HN) return;
    int n = idx / HN, h = idx - n * HN;
    const float4* f4 = (const float4*)(feat + (size_t)n * (HN * DHD) + h * DHD);
    const float4* al4 = (const float4*)(al + h * DHD);
    const float4* ar4 = (const float4*)(ar + h * DHD);
    float sl = 0.f, sr = 0.f;
#pragma unroll
    for (int d = 0; d < DHD / 4; ++d) {
        float4 fv = f4[d], lv = al4[d], rv = ar4[d];
        sl += fv.x * lv.x + fv.y * lv.y + fv.z * lv.z + fv.w * lv.w;
        sr += fv.x * rv.x + fv.y * rv.y + fv.z * rv.z + fv.w * rv.w;
    }
    el[idx] = sl; er[idx] = sr;
}

// ---------- edge pass 1: a = exp(leaky_relu(el[src]+er[dst])); denom[dst] += a ----------
// (segment_max dropped: alpha is mathematically invariant to it and |e| < ~3 here)
template<int HN>
__global__ __launch_bounds__(TPB) void edge_exp_kernel(
    const float* __restrict__ el, const float* __restrict__ er,
    const int* __restrict__ src, const int* __restrict__ dst,
    float* __restrict__ a, float* __restrict__ denom, int Etot)
{
    int idx = blockIdx.x * TPB + threadIdx.x;
    if (idx >= Etot * HN) return;
    int i = idx / HN, h = idx - i * HN;
    int s = src[i], d = dst[i];
    float e = el[s * HN + h] + er[d * HN + h];
    e = e > 0.f ? e : 0.2f * e;
    float av = __expf(e);
    a[idx] = av;
    atomicAdd(&denom[d * HN + h], av);
}

// ---------- edge pass 2 GAT1: out[dst, h, :] += alpha * feat[src, h, :]  (4 heads x 64) ----------
__global__ __launch_bounds__(TPB) void gat1_aggregate(
    const float* __restrict__ a, const float* __restrict__ den,
    const float* __restrict__ feat, const int* __restrict__ src,
    const int* __restrict__ dst, float* __restrict__ out, int Etot)
{
    int i = blockIdx.x * 4 + (threadIdx.x >> 6);   // one wave per edge
    if (i >= Etot) return;
    int lane = threadIdx.x & 63;
    int s = src[i], d = dst[i];
    int h = lane >> 4;                              // 16 lanes per head (4 floats each)
    float alpha = a[i * 4 + h] / den[d * 4 + h];
    float4 fv = *(const float4*)(feat + (size_t)s * 256 + lane * 4);
    float* op = out + (size_t)d * 256 + lane * 4;
    atomicAdd(op + 0, alpha * fv.x);
    atomicAdd(op + 1, alpha * fv.y);
    atomicAdd(op + 2, alpha * fv.z);
    atomicAdd(op + 3, alpha * fv.w);
}

// ---------- edge pass 2 GAT2: out[dst, :] += alpha * feat[src, :]  (8 cols) ----------
__global__ __launch_bounds__(TPB) void gat2_aggregate(
    const float* __restrict__ a, const float* __restrict__ den,
    const float* __restrict__ feat, const int* __restrict__ src,
    const int* __restrict__ dst, float* __restrict__ out, int Etot)
{
    int idx = blockIdx.x * TPB + threadIdx.x;
    if (idx >= Etot * 8) return;
    int i = idx >> 3, j = idx & 7;
    int s = src[i], d = dst[i];
    float alpha = a[i] / den[d];
    atomicAdd(&out[d * 8 + j], alpha * feat[s * 8 + j]);
}

// ---------- elu(out1 + bias) in place, float4 ----------
__global__ __launch_bounds__(TPB) void elu_bias_kernel(
    float* __restrict__ h, const float* __restrict__ bias, int total4)
{
    int idx = blockIdx.x * TPB + threadIdx.x;
    if (idx >= total4) return;
    float4 v = ((float4*)h)[idx];
    float4 bv = ((const float4*)bias)[idx & 63];   // row = 256 floats = 64 float4
    v.x += bv.x; v.y += bv.y; v.z += bv.z; v.w += bv.w;
    v.x = v.x > 0.f ? v.x : __expf(v.x) - 1.f;
    v.y = v.y > 0.f ? v.y : __expf(v.y) - 1.f;
    v.z = v.z > 0.f ? v.z : __expf(v.z) - 1.f;
    v.w = v.w > 0.f ? v.w : __expf(v.w) - 1.f;
    ((float4*)h)[idx] = v;
}

// ---------- gates + combine + output GEMM + softmax ----------
__global__ __launch_bounds__(TPB) void final_kernel(
    const float* __restrict__ wide, const float* __restrict__ deep,
    const float* __restrict__ out2, const int* __restrict__ Xid,
    const float* __restrict__ g2bias,
    const float* __restrict__ g1w, const float* __restrict__ g1b,
    const float* __restrict__ g2w, const float* __restrict__ g2b,
    const float* __restrict__ g3w, const float* __restrict__ g3b,
    const float* __restrict__ goutw, const float* __restrict__ goutb,
    float* __restrict__ out, int B)
{
    int b = blockIdx.x * TPB + threadIdx.x;
    if (b >= B) return;
    float w8[8], d8[8], g8[8];
    {
        float4 t0 = *(const float4*)(wide + (size_t)b * 8);
        float4 t1 = *(const float4*)(wide + (size_t)b * 8 + 4);
        w8[0] = t0.x; w8[1] = t0.y; w8[2] = t0.z; w8[3] = t0.w;
        w8[4] = t1.x; w8[5] = t1.y; w8[6] = t1.z; w8[7] = t1.w;
        t0 = *(const float4*)(deep + (size_t)b * 8);
        t1 = *(const float4*)(deep + (size_t)b * 8 + 4);
        d8[0] = t0.x; d8[1] = t0.y; d8[2] = t0.z; d8[3] = t0.w;
        d8[4] = t1.x; d8[5] = t1.y; d8[6] = t1.z; d8[7] = t1.w;
    }
    int commit = Xid[b * 2 + 1];
#pragma unroll
    for (int j = 0; j < 8; ++j) g8[j] = out2[(size_t)commit * 8 + j] + g2bias[j];
    float s1 = g1b[0], s2 = g2b[0], s3 = g3b[0];
#pragma unroll
    for (int j = 0; j < 8; ++j) { s1 += w8[j] * g1w[j]; s2 += d8[j] * g2w[j]; s3 += g8[j] * g3w[j]; }
    float aw = sigmoidf_(s1), bw = sigmoidf_(s2), cw = sigmoidf_(s3);
    float inv_tot = 1.f / (aw + bw + cw);
    float an = aw * inv_tot, bn = bw * inv_tot, cn = cw * inv_tot;
    float o0 = goutb[0], o1 = goutb[1];
#pragma unroll
    for (int j = 0; j < 8; ++j) {
        float c0 = an * w8[j]; o0 += goutw[j] * c0;      o1 += goutw[24 + j] * c0;
        float c1 = bn * d8[j]; o0 += goutw[8 + j] * c1;  o1 += goutw[32 + j] * c1;
        float c2 = cn * g8[j]; o0 += goutw[16 + j] * c2; o1 += goutw[40 + j] * c2;
    }
    float mx = fmaxf(o0, o1);
    float e0 = __expf(o0 - mx), e1 = __expf(o1 - mx);
    float inv = 1.f / (e0 + e1);
    out[(size_t)b * 2] = e0 * inv;
    out[(size_t)b * 2 + 1] = e1 * inv;
}

extern "C" void kernel_launch(void* const* d_in, const int* in_sizes, int n_in,
                              void* d_out, int out_size, void* d_ws, size_t ws_size,
                              hipStream_t stream)
{
    const int*   Xid    = (const int*)d_in[0];
    const int*   Xs     = (const int*)d_in[1];
    const float* Xd     = (const float*)d_in[2];
    const float* emb    = (const float*)d_in[3];
    const float* gfeat  = (const float*)d_in[4];
    const int*   src    = (const int*)d_in[5];
    const int*   dst    = (const int*)d_in[6];
    const float* wide_w = (const float*)d_in[7];
    const float* wide_b = (const float*)d_in[8];
    const float* lin1_w = (const float*)d_in[9];
    const float* lin1_b = (const float*)d_in[10];
    const float* bn1_g  = (const float*)d_in[11];
    const float* bn1_b  = (const float*)d_in[12];
    const float* bn1_m  = (const float*)d_in[13];
    const float* bn1_v  = (const float*)d_in[14];
    const float* lin2_w = (const float*)d_in[15];
    const float* lin2_b = (const float*)d_in[16];
    const float* bn2_g  = (const float*)d_in[17];
    const float* bn2_b  = (const float*)d_in[18];
    const float* bn2_m  = (const float*)d_in[19];
    const float* bn2_v  = (const float*)d_in[20];
    const float* dnn_w  = (const float*)d_in[21];
    const float* dnn_b  = (const float*)d_in[22];
    const float* gat1_w = (const float*)d_in[23];
    const float* gat1_al = (const float*)d_in[24];
    const float* gat1_ar = (const float*)d_in[25];
    const float* gat1_bias = (const float*)d_in[26];
    const float* gat2_w = (const float*)d_in[27];
    const float* gat2_al = (const float*)d_in[28];
    const float* gat2_ar = (const float*)d_in[29];
    const float* gat2_bias = (const float*)d_in[30];
    const float* g1w = (const float*)d_in[31];
    const float* g1b = (const float*)d_in[32];
    const float* g2w = (const float*)d_in[33];
    const float* g2b = (const float*)d_in[34];
    const float* g3w = (const float*)d_in[35];
    const float* g3b = (const float*)d_in[36];
    const float* goutw = (const float*)d_in[37];
    const float* goutb = (const float*)d_in[38];

    const int B    = in_sizes[0] / 2;     // 16384
    const int Nn   = in_sizes[4] / 128;   // 50000
    const int Etot = in_sizes[5];         // 450000

    // ---- workspace layout (floats). Deep-path buffers alias under out1:
    //   [0 .. B*224)            x
    //   [B*224 .. +B*256)       d1
    //   [.. +B*256)             d2            (total 12,058,624 < Nn*256)
    //   [0 .. Nn*256)           out1/h1       (memset AFTER deep path retires)
    //   [Nn*256 ..)             feat1, then the small buffers
    float* ws    = (float*)d_ws;
    float* xb    = ws;
    float* d1    = xb + (size_t)B * 224;
    float* d2    = d1 + (size_t)B * 256;
    float* out1  = ws;                        // Nn*256
    float* feat1 = ws + (size_t)Nn * 256;     // Nn*256
    float* wide  = feat1 + (size_t)Nn * 256;
    float* deep  = wide + (size_t)B * 8;
    float* el1   = deep + (size_t)B * 8;
    float* er1   = el1 + (size_t)Nn * 4;
    float* a1    = er1 + (size_t)Nn * 4;
    float* den1  = a1 + (size_t)Etot * 4;
    float* feat2 = den1 + (size_t)Nn * 4;
    float* el2   = feat2 + (size_t)Nn * 8;
    float* er2   = el2 + Nn;
    float* a2    = er2 + Nn;
    float* den2  = a2 + Etot;
    float* out2  = den2 + Nn;

    // zero the non-aliased accumulators up front
    hipMemsetAsync(den1, 0, (size_t)Nn * 4 * sizeof(float), stream);
    hipMemsetAsync(den2, 0, (size_t)Nn * sizeof(float), stream);
    hipMemsetAsync(out2, 0, (size_t)Nn * 8 * sizeof(float), stream);

    // ---- deep path ----
    build_x_kernel<<<(B * 224 + TPB - 1) / TPB, TPB, 0, stream>>>(Xs, Xd, emb, xb, B);
    gemm_nt<true><<<dim3((B + 63) / 64, 4), 256, 0, stream>>>(
        xb, lin1_w, lin1_b, bn1_g, bn1_b, bn1_m, bn1_v, d1, B, 256, 224);
    gemm_nt<true><<<dim3((B + 63) / 64, 4), 256, 0, stream>>>(
        d1, lin2_w, lin2_b, bn2_g, bn2_b, bn2_m, bn2_v, d2, B, 256, 256);
    gemm_n8<<<(B * 8 + TPB - 1) / TPB, TPB, 0, stream>>>(Xd, wide_w, wide_b, wide, B, 64);
    gemm_n8<<<(B * 8 + TPB - 1) / TPB, TPB, 0, stream>>>(d2, dnn_w, dnn_b, deep, B, 256);

    // deep path done -> out1 region (aliases x/d1/d2) is free now
    hipMemsetAsync(out1, 0, (size_t)Nn * 256 * sizeof(float), stream);

    // ---- GAT layer 1 ----
    gemm_nt<false><<<dim3((Nn + 63) / 64, 4), 256, 0, stream>>>(
        gfeat, gat1_w, nullptr, nullptr, nullptr, nullptr, nullptr, feat1, Nn, 256, 128);
    attn_coef_kernel<4, 64><<<(Nn * 4 + TPB - 1) / TPB, TPB, 0, stream>>>(
        feat1, gat1_al, gat1_ar, el1, er1, Nn);
    edge_exp_kernel<4><<<(Etot * 4 + TPB - 1) / TPB, TPB, 0, stream>>>(
        el1, er1, src, dst, a1, den1, Etot);
    gat1_aggregate<<<(Etot + 3) / 4, TPB, 0, stream>>>(a1, den1, feat1, src, dst, out1, Etot);
    elu_bias_kernel<<<(Nn * 64 + TPB - 1) / TPB, TPB, 0, stream>>>(out1, gat1_bias, Nn * 64);

    // ---- GAT layer 2 ----
    gemm_n8<<<(Nn * 8 + TPB - 1) / TPB, TPB, 0, stream>>>(out1, gat2_w, nullptr, feat2, Nn, 256);
    attn_coef_kernel<1, 8><<<(Nn + TPB - 1) / TPB, TPB, 0, stream>>>(
        feat2, gat2_al, gat2_ar, el2, er2, Nn);
    edge_exp_kernel<1><<<(Etot + TPB - 1) / TPB, TPB, 0, stream>>>(
        el2, er2, src, dst, a2, den2, Etot);
    gat2_aggregate<<<(Etot * 8 + TPB - 1) / TPB, TPB, 0, stream>>>(
        a2, den2, feat2, src, dst, out2, Etot);

    // ---- gates + output ----
    final_kernel<<<(B + TPB - 1) / TPB, TPB, 0, stream>>>(
        wide, deep, out2, Xid, gat2_bias, g1w, g1b, g2w, g2b, g3w, g3b, goutw, goutb,
        (float*)d_out, B);
}

// Round 2
// 631.169 us; speedup vs baseline: 3.1854x; 3.1854x over previous
//
#include <hip/hip_runtime.h>

#define TPB 256
constexpr float BN_EPS = 1e-5f;

__device__ __forceinline__ float sigmoidf_(float x) { return 1.f / (1.f + __expf(-x)); }

// ---------- build x = [sparse_embed (20*8) | dense (64)] : (B, 224) ----------
__global__ __launch_bounds__(TPB) void build_x_kernel(
    const int* __restrict__ Xs, const float* __restrict__ Xd,
    const float* __restrict__ emb, float* __restrict__ x, int B)
{
    int idx = blockIdx.x * TPB + threadIdx.x;
    if (idx >= B * 224) return;
    int b = idx / 224, c = idx - b * 224;
    float v;
    if (c < 160) {
        int s = c >> 3, j = c & 7;
        int e = Xs[b * 20 + s];
        v = emb[((size_t)s * 1000 + e) * 8 + j];
    } else {
        v = Xd[b * 64 + (c - 160)];
    }
    x[idx] = v;
}

// ---------- tiled fp32 GEMM: C(M,N) = A(M,K) @ W(N,K)^T (+bias)(+bn+relu) ----------
template<bool BNRELU>
__global__ __launch_bounds__(256) void gemm_nt(
    const float* __restrict__ A, const float* __restrict__ W,
    const float* __restrict__ bias,
    const float* __restrict__ g, const float* __restrict__ bb,
    const float* __restrict__ bm, const float* __restrict__ bv,
    float* __restrict__ C, int M, int N, int K)
{
    constexpr int SL = 68;
    __shared__ float As[32 * SL];
    __shared__ float Ws[32 * SL];
    int tid = threadIdx.x;
    int m0 = blockIdx.x * 64, n0 = blockIdx.y * 64;
    int tm = (tid & 15) * 4, tn = (tid >> 4) * 4;
    float acc[4][4] = {};
    for (int k0 = 0; k0 < K; k0 += 32) {
#pragma unroll
        for (int i = 0; i < 2; ++i) {
            int idx = tid + i * 256;
            int r = idx >> 3, kv = idx & 7;
            int kk = kv * 4;
            float4 av = make_float4(0.f, 0.f, 0.f, 0.f);
            int gm = m0 + r;
            if (gm < M) av = *(const float4*)(A + (size_t)gm * K + k0 + kk);
            As[(kk + 0) * SL + r] = av.x; As[(kk + 1) * SL + r] = av.y;
            As[(kk + 2) * SL + r] = av.z; As[(kk + 3) * SL + r] = av.w;
            float4 wv = make_float4(0.f, 0.f, 0.f, 0.f);
            int gn = n0 + r;
            if (gn < N) wv = *(const float4*)(W + (size_t)gn * K + k0 + kk);
            Ws[(kk + 0) * SL + r] = wv.x; Ws[(kk + 1) * SL + r] = wv.y;
            Ws[(kk + 2) * SL + r] = wv.z; Ws[(kk + 3) * SL + r] = wv.w;
        }
        __syncthreads();
#pragma unroll
        for (int k = 0; k < 32; ++k) {
            float4 a = *(const float4*)&As[k * SL + tm];
            float4 b = *(const float4*)&Ws[k * SL + tn];
            acc[0][0] += a.x * b.x; acc[0][1] += a.x * b.y; acc[0][2] += a.x * b.z; acc[0][3] += a.x * b.w;
            acc[1][0] += a.y * b.x; acc[1][1] += a.y * b.y; acc[1][2] += a.y * b.z; acc[1][3] += a.y * b.w;
            acc[2][0] += a.z * b.x; acc[2][1] += a.z * b.y; acc[2][2] += a.z * b.z; acc[2][3] += a.z * b.w;
            acc[3][0] += a.w * b.x; acc[3][1] += a.w * b.y; acc[3][2] += a.w * b.z; acc[3][3] += a.w * b.w;
        }
        __syncthreads();
    }
#pragma unroll
    for (int i = 0; i < 4; ++i) {
        int gm = m0 + tm + i;
        if (gm >= M) continue;
#pragma unroll
        for (int j = 0; j < 4; ++j) {
            int gn = n0 + tn + j;
            if (gn >= N) continue;
            float t = acc[i][j];
            if (bias) t += bias[gn];
            if (BNRELU) {
                float sc = g[gn] * rsqrtf(bv[gn] + BN_EPS);
                t = t * sc + (bb[gn] - bm[gn] * sc);
                t = fmaxf(t, 0.f);
            }
            C[(size_t)gm * N + gn] = t;
        }
    }
}

// ---------- C(M,8) = A(M,K) @ W(8,K)^T + bias ----------
__global__ __launch_bounds__(TPB) void gemm_n8(
    const float* __restrict__ A, const float* __restrict__ Wt,
    const float* __restrict__ bias, float* __restrict__ C, int M, int K)
{
    int idx = blockIdx.x * TPB + threadIdx.x;
    if (idx >= M * 8) return;
    int r = idx >> 3, j = idx & 7;
    const float4* a4 = (const float4*)(A + (size_t)r * K);
    const float4* w4 = (const float4*)(Wt + (size_t)j * K);
    float s = 0.f;
    int k4 = K >> 2;
    for (int k = 0; k < k4; ++k) {
        float4 av = a4[k], wv = w4[k];
        s += av.x * wv.x + av.y * wv.y + av.z * wv.z + av.w * wv.w;
    }
    if (bias) s += bias[j];
    C[idx] = s;
}

// ---------- per-node attention coefficients: el/er (N, HN) ----------
template<int HN, int DHD>
__global__ __launch_bounds__(TPB) void attn_coef_kernel(
    const float* __restrict__ feat, const float* __restrict__ al,
    const float* __restrict__ ar, float* __restrict__ el, float* __restrict__ er, int Nn)
{
    int idx = blockIdx.x * TPB + threadIdx.x;
    if (idx >= Nn * HN) return;
    int n = idx / HN, h = idx - n * HN;
    const float4* f4 = (const float4*)(feat + (size_t)n * (HN * DHD) + h * DHD);
    const float4* al4 = (const float4*)(al + h * DHD);
    const float4* ar4 = (const float4*)(ar + h * DHD);
    float sl = 0.f, sr = 0.f;
#pragma unroll
    for (int d = 0; d < DHD / 4; ++d) {
        float4 fv = f4[d], lv = al4[d], rv = ar4[d];
        sl += fv.x * lv.x + fv.y * lv.y + fv.z * lv.z + fv.w * lv.w;
        sr += fv.x * rv.x + fv.y * rv.y + fv.z * rv.z + fv.w * rv.w;
    }
    el[idx] = sl; er[idx] = sr;
}

// ================= CSR build (by dst) =================
__global__ __launch_bounds__(TPB) void hist_kernel(
    const int* __restrict__ dst, int* __restrict__ cnt, int E)
{
    int i = blockIdx.x * TPB + threadIdx.x;
    if (i >= E) return;
    atomicAdd(&cnt[dst[i]], 1);
}

// single-block exclusive scan: rowstart[0]=0, rowstart[i+1]=sum(cnt[0..i])
__global__ __launch_bounds__(1024) void scan_kernel(
    const int* __restrict__ cnt, int* __restrict__ rowstart, int Nn)
{
    __shared__ int buf[1024];
    __shared__ int carry;
    int tid = threadIdx.x;
    if (tid == 0) { carry = 0; rowstart[0] = 0; }
    __syncthreads();
    for (int base = 0; base < Nn; base += 1024) {
        int i = base + tid;
        int v = (i < Nn) ? cnt[i] : 0;
        buf[tid] = v;
        __syncthreads();
#pragma unroll
        for (int off = 1; off < 1024; off <<= 1) {
            int t = (tid >= off) ? buf[tid - off] : 0;
            __syncthreads();
            buf[tid] += t;
            __syncthreads();
        }
        int c = carry;
        if (i < Nn) rowstart[i + 1] = c + buf[tid];
        __syncthreads();
        if (tid == 0) carry = c + buf[1023];
        __syncthreads();
    }
}

// scatter src node ids into CSR slots (order within a row is arbitrary — sum commutes)
__global__ __launch_bounds__(TPB) void scatter_kernel(
    const int* __restrict__ src, const int* __restrict__ dst,
    int* __restrict__ cursor, int* __restrict__ esrc, int E)
{
    int i = blockIdx.x * TPB + threadIdx.x;
    if (i >= E) return;
    int pos = atomicAdd(&cursor[dst[i]], 1);
    esrc[pos] = src[i];
}

// ========== GAT1 gather: one wave per dst node; fused softmax-denom + ELU + bias ==========
__global__ __launch_bounds__(TPB) void gat1_gather(
    const float* __restrict__ feat, const float* __restrict__ el,
    const float* __restrict__ er, const int* __restrict__ rowstart,
    const int* __restrict__ esrc, const float* __restrict__ bias,
    float* __restrict__ out, int Nn)
{
    int n = blockIdx.x * 4 + (threadIdx.x >> 6);
    if (n >= Nn) return;
    int lane = threadIdx.x & 63;
    int h = lane >> 4;
    int c = h * 64 + (lane & 15) * 4;   // this lane's 4 columns within the 256-wide row
    float erv = er[n * 4 + h];
    int beg = rowstart[n], end = rowstart[n + 1];
    float4 acc = make_float4(0.f, 0.f, 0.f, 0.f);
    float dsum = 0.f;
    for (int e = beg; e < end; ++e) {
        int s = esrc[e];
        float ev = el[s * 4 + h] + erv;
        ev = ev > 0.f ? ev : 0.2f * ev;
        float av = __expf(ev);
        dsum += av;
        float4 fv = *(const float4*)(feat + (size_t)s * 256 + c);
        acc.x += av * fv.x; acc.y += av * fv.y; acc.z += av * fv.z; acc.w += av * fv.w;
    }
    float inv = 1.f / dsum;   // every node has a self-loop -> dsum > 0
    float4 bv = *(const float4*)(bias + c);
    float4 o;
    o.x = acc.x * inv + bv.x; o.y = acc.y * inv + bv.y;
    o.z = acc.z * inv + bv.z; o.w = acc.w * inv + bv.w;
    o.x = o.x > 0.f ? o.x : __expf(o.x) - 1.f;
    o.y = o.y > 0.f ? o.y : __expf(o.y) - 1.f;
    o.z = o.z > 0.f ? o.z : __expf(o.z) - 1.f;
    o.w = o.w > 0.f ? o.w : __expf(o.w) - 1.f;
    *(float4*)(out + (size_t)n * 256 + c) = o;
}

// ========== GAT2 gather: 8 threads per dst node ==========
__global__ __launch_bounds__(TPB) void gat2_gather(
    const float* __restrict__ feat2, const float* __restrict__ el,
    const float* __restrict__ er, const int* __restrict__ rowstart,
    const int* __restrict__ esrc, float* __restrict__ out2, int Nn)
{
    int idx = blockIdx.x * TPB + threadIdx.x;
    if (idx >= Nn * 8) return;
    int n = idx >> 3, j = idx & 7;
    float erv = er[n];
    int beg = rowstart[n], end = rowstart[n + 1];
    float acc = 0.f, dsum = 0.f;
    for (int e = beg; e < end; ++e) {
        int s = esrc[e];
        float ev = el[s] + erv;
        ev = ev > 0.f ? ev : 0.2f * ev;
        float av = __expf(ev);
        dsum += av;
        acc += av * feat2[(size_t)s * 8 + j];
    }
    out2[idx] = acc / dsum;
}

// ---------- gates + combine + output GEMM + softmax ----------
__global__ __launch_bounds__(TPB) void final_kernel(
    const float* __restrict__ wide, const float* __restrict__ deep,
    const float* __restrict__ out2, const int* __restrict__ Xid,
    const float* __restrict__ g2bias,
    const float* __restrict__ g1w, const float* __restrict__ g1b,
    const float* __restrict__ g2w, const float* __restrict__ g2b,
    const float* __restrict__ g3w, const float* __restrict__ g3b,
    const float* __restrict__ goutw, const float* __restrict__ goutb,
    float* __restrict__ out, int B)
{
    int b = blockIdx.x * TPB + threadIdx.x;
    if (b >= B) return;
    float w8[8], d8[8], g8[8];
    {
        float4 t0 = *(const float4*)(wide + (size_t)b * 8);
        float4 t1 = *(const float4*)(wide + (size_t)b * 8 + 4);
        w8[0] = t0.x; w8[1] = t0.y; w8[2] = t0.z; w8[3] = t0.w;
        w8[4] = t1.x; w8[5] = t1.y; w8[6] = t1.z; w8[7] = t1.w;
        t0 = *(const float4*)(deep + (size_t)b * 8);
        t1 = *(const float4*)(deep + (size_t)b * 8 + 4);
        d8[0] = t0.x; d8[1] = t0.y; d8[2] = t0.z; d8[3] = t0.w;
        d8[4] = t1.x; d8[5] = t1.y; d8[6] = t1.z; d8[7] = t1.w;
    }
    int commit = Xid[b * 2 + 1];
#pragma unroll
    for (int j = 0; j < 8; ++j) g8[j] = out2[(size_t)commit * 8 + j] + g2bias[j];
    float s1 = g1b[0], s2 = g2b[0], s3 = g3b[0];
#pragma unroll
    for (int j = 0; j < 8; ++j) { s1 += w8[j] * g1w[j]; s2 += d8[j] * g2w[j]; s3 += g8[j] * g3w[j]; }
    float aw = sigmoidf_(s1), bw = sigmoidf_(s2), cw = sigmoidf_(s3);
    float inv_tot = 1.f / (aw + bw + cw);
    float an = aw * inv_tot, bn = bw * inv_tot, cn = cw * inv_tot;
    float o0 = goutb[0], o1 = goutb[1];
#pragma unroll
    for (int j = 0; j < 8; ++j) {
        float c0 = an * w8[j]; o0 += goutw[j] * c0;      o1 += goutw[24 + j] * c0;
        float c1 = bn * d8[j]; o0 += goutw[8 + j] * c1;  o1 += goutw[32 + j] * c1;
        float c2 = cn * g8[j]; o0 += goutw[16 + j] * c2; o1 += goutw[40 + j] * c2;
    }
    float mx = fmaxf(o0, o1);
    float e0 = __expf(o0 - mx), e1 = __expf(o1 - mx);
    float inv = 1.f / (e0 + e1);
    out[(size_t)b * 2] = e0 * inv;
    out[(size_t)b * 2 + 1] = e1 * inv;
}

extern "C" void kernel_launch(void* const* d_in, const int* in_sizes, int n_in,
                              void* d_out, int out_size, void* d_ws, size_t ws_size,
                              hipStream_t stream)
{
    const int*   Xid    = (const int*)d_in[0];
    const int*   Xs     = (const int*)d_in[1];
    const float* Xd     = (const float*)d_in[2];
    const float* emb    = (const float*)d_in[3];
    const float* gfeat  = (const float*)d_in[4];
    const int*   src    = (const int*)d_in[5];
    const int*   dst    = (const int*)d_in[6];
    const float* wide_w = (const float*)d_in[7];
    const float* wide_b = (const float*)d_in[8];
    const float* lin1_w = (const float*)d_in[9];
    const float* lin1_b = (const float*)d_in[10];
    const float* bn1_g  = (const float*)d_in[11];
    const float* bn1_b  = (const float*)d_in[12];
    const float* bn1_m  = (const float*)d_in[13];
    const float* bn1_v  = (const float*)d_in[14];
    const float* lin2_w = (const float*)d_in[15];
    const float* lin2_b = (const float*)d_in[16];
    const float* bn2_g  = (const float*)d_in[17];
    const float* bn2_b  = (const float*)d_in[18];
    const float* bn2_m  = (const float*)d_in[19];
    const float* bn2_v  = (const float*)d_in[20];
    const float* dnn_w  = (const float*)d_in[21];
    const float* dnn_b  = (const float*)d_in[22];
    const float* gat1_w = (const float*)d_in[23];
    const float* gat1_al = (const float*)d_in[24];
    const float* gat1_ar = (const float*)d_in[25];
    const float* gat1_bias = (const float*)d_in[26];
    const float* gat2_w = (const float*)d_in[27];
    const float* gat2_al = (const float*)d_in[28];
    const float* gat2_ar = (const float*)d_in[29];
    const float* gat2_bias = (const float*)d_in[30];
    const float* g1w = (const float*)d_in[31];
    const float* g1b = (const float*)d_in[32];
    const float* g2w = (const float*)d_in[33];
    const float* g2b = (const float*)d_in[34];
    const float* g3w = (const float*)d_in[35];
    const float* g3b = (const float*)d_in[36];
    const float* goutw = (const float*)d_in[37];
    const float* goutb = (const float*)d_in[38];

    const int B    = in_sizes[0] / 2;     // 16384
    const int Nn   = in_sizes[4] / 128;   // 50000
    const int Etot = in_sizes[5];         // 450000

    // ---- workspace layout (floats); deep-path x/d1/d2 alias under out1 ----
    float* ws    = (float*)d_ws;
    float* xb    = ws;                         // B*224   (aliases out1)
    float* d1    = xb + (size_t)B * 224;       // B*256
    float* d2    = d1 + (size_t)B * 256;       // B*256   (ends at 12.06M < Nn*256)
    float* out1  = ws;                         // Nn*256  (written by gat1_gather, all rows)
    float* feat1 = ws + (size_t)Nn * 256;      // Nn*256
    float* wide  = feat1 + (size_t)Nn * 256;   // B*8
    float* deep  = wide + (size_t)B * 8;       // B*8
    float* el1   = deep + (size_t)B * 8;       // Nn*4
    float* er1   = el1 + (size_t)Nn * 4;       // Nn*4
    float* feat2 = er1 + (size_t)Nn * 4;       // Nn*8
    float* el2   = feat2 + (size_t)Nn * 8;     // Nn
    float* er2   = el2 + Nn;                   // Nn
    float* out2  = er2 + Nn;                   // Nn*8
    int* rowstart = (int*)(out2 + (size_t)Nn * 8);  // Nn+1
    int* cnt      = rowstart + (Nn + 1);            // Nn+1
    int* cursor   = cnt + (Nn + 1);                 // Nn
    int* esrc     = cursor + Nn;                    // Etot

    // ---- CSR build (shared by both GAT layers) ----
    hipMemsetAsync(cnt, 0, (size_t)(Nn + 1) * sizeof(int), stream);
    hist_kernel<<<(Etot + TPB - 1) / TPB, TPB, 0, stream>>>(dst, cnt, Etot);
    scan_kernel<<<1, 1024, 0, stream>>>(cnt, rowstart, Nn);
    hipMemcpyAsync(cursor, rowstart, (size_t)Nn * sizeof(int),
                   hipMemcpyDeviceToDevice, stream);
    scatter_kernel<<<(Etot + TPB - 1) / TPB, TPB, 0, stream>>>(src, dst, cursor, esrc, Etot);

    // ---- deep path (uses the region aliased under out1; must finish before gat1_gather) ----
    build_x_kernel<<<(B * 224 + TPB - 1) / TPB, TPB, 0, stream>>>(Xs, Xd, emb, xb, B);
    gemm_nt<true><<<dim3((B + 63) / 64, 4), 256, 0, stream>>>(
        xb, lin1_w, lin1_b, bn1_g, bn1_b, bn1_m, bn1_v, d1, B, 256, 224);
    gemm_nt<true><<<dim3((B + 63) / 64, 4), 256, 0, stream>>>(
        d1, lin2_w, lin2_b, bn2_g, bn2_b, bn2_m, bn2_v, d2, B, 256, 256);
    gemm_n8<<<(B * 8 + TPB - 1) / TPB, TPB, 0, stream>>>(Xd, wide_w, wide_b, wide, B, 64);
    gemm_n8<<<(B * 8 + TPB - 1) / TPB, TPB, 0, stream>>>(d2, dnn_w, dnn_b, deep, B, 256);

    // ---- GAT layer 1 ----
    gemm_nt<false><<<dim3((Nn + 63) / 64, 4), 256, 0, stream>>>(
        gfeat, gat1_w, nullptr, nullptr, nullptr, nullptr, nullptr, feat1, Nn, 256, 128);
    attn_coef_kernel<4, 64><<<(Nn * 4 + TPB - 1) / TPB, TPB, 0, stream>>>(
        feat1, gat1_al, gat1_ar, el1, er1, Nn);
    gat1_gather<<<(Nn + 3) / 4, TPB, 0, stream>>>(
        feat1, el1, er1, rowstart, esrc, gat1_bias, out1, Nn);

    // ---- GAT layer 2 ----
    gemm_n8<<<(Nn * 8 + TPB - 1) / TPB, TPB, 0, stream>>>(out1, gat2_w, nullptr, feat2, Nn, 256);
    attn_coef_kernel<1, 8><<<(Nn + TPB - 1) / TPB, TPB, 0, stream>>>(
        feat2, gat2_al, gat2_ar, el2, er2, Nn);
    gat2_gather<<<(Nn * 8 + TPB - 1) / TPB, TPB, 0, stream>>>(
        feat2, el2, er2, rowstart, esrc, out2, Nn);

    // ---- gates + output ----
    final_kernel<<<(B + TPB - 1) / TPB, TPB, 0, stream>>>(
        wide, deep, out2, Xid, gat2_bias, g1w, g1b, g2w, g2b, g3w, g3b, goutw, goutb,
        (float*)d_out, B);
}

// Round 3
// 544.667 us; speedup vs baseline: 3.6913x; 1.1588x over previous
//
#include <hip/hip_runtime.h>

#define TPB 256
constexpr float BN_EPS = 1e-5f;

__device__ __forceinline__ float sigmoidf_(float x) { return 1.f / (1.f + __expf(-x)); }

// ---------- build x = [sparse_embed (20*8) | dense (64)] : (B, 224) ----------
__global__ __launch_bounds__(TPB) void build_x_kernel(
    const int* __restrict__ Xs, const float* __restrict__ Xd,
    const float* __restrict__ emb, float* __restrict__ x, int B)
{
    int idx = blockIdx.x * TPB + threadIdx.x;
    if (idx >= B * 224) return;
    int b = idx / 224, c = idx - b * 224;
    float v;
    if (c < 160) {
        int s = c >> 3, j = c & 7;
        int e = Xs[b * 20 + s];
        v = emb[((size_t)s * 1000 + e) * 8 + j];
    } else {
        v = Xd[b * 64 + (c - 160)];
    }
    x[idx] = v;
}

// ---------- tiled fp32 GEMM: C(M,N) = A(M,K) @ W(N,K)^T (+bias)(+bn+relu) ----------
template<bool BNRELU>
__global__ __launch_bounds__(256) void gemm_nt(
    const float* __restrict__ A, const float* __restrict__ W,
    const float* __restrict__ bias,
    const float* __restrict__ g, const float* __restrict__ bb,
    const float* __restrict__ bm, const float* __restrict__ bv,
    float* __restrict__ C, int M, int N, int K)
{
    constexpr int SL = 68;
    __shared__ float As[32 * SL];
    __shared__ float Ws[32 * SL];
    int tid = threadIdx.x;
    int m0 = blockIdx.x * 64, n0 = blockIdx.y * 64;
    int tm = (tid & 15) * 4, tn = (tid >> 4) * 4;
    float acc[4][4] = {};
    for (int k0 = 0; k0 < K; k0 += 32) {
#pragma unroll
        for (int i = 0; i < 2; ++i) {
            int idx = tid + i * 256;
            int r = idx >> 3, kv = idx & 7;
            int kk = kv * 4;
            float4 av = make_float4(0.f, 0.f, 0.f, 0.f);
            int gm = m0 + r;
            if (gm < M) av = *(const float4*)(A + (size_t)gm * K + k0 + kk);
            As[(kk + 0) * SL + r] = av.x; As[(kk + 1) * SL + r] = av.y;
            As[(kk + 2) * SL + r] = av.z; As[(kk + 3) * SL + r] = av.w;
            float4 wv = make_float4(0.f, 0.f, 0.f, 0.f);
            int gn = n0 + r;
            if (gn < N) wv = *(const float4*)(W + (size_t)gn * K + k0 + kk);
            Ws[(kk + 0) * SL + r] = wv.x; Ws[(kk + 1) * SL + r] = wv.y;
            Ws[(kk + 2) * SL + r] = wv.z; Ws[(kk + 3) * SL + r] = wv.w;
        }
        __syncthreads();
#pragma unroll
        for (int k = 0; k < 32; ++k) {
            float4 a = *(const float4*)&As[k * SL + tm];
            float4 b = *(const float4*)&Ws[k * SL + tn];
            acc[0][0] += a.x * b.x; acc[0][1] += a.x * b.y; acc[0][2] += a.x * b.z; acc[0][3] += a.x * b.w;
            acc[1][0] += a.y * b.x; acc[1][1] += a.y * b.y; acc[1][2] += a.y * b.z; acc[1][3] += a.y * b.w;
            acc[2][0] += a.z * b.x; acc[2][1] += a.z * b.y; acc[2][2] += a.z * b.z; acc[2][3] += a.z * b.w;
            acc[3][0] += a.w * b.x; acc[3][1] += a.w * b.y; acc[3][2] += a.w * b.z; acc[3][3] += a.w * b.w;
        }
        __syncthreads();
    }
#pragma unroll
    for (int i = 0; i < 4; ++i) {
        int gm = m0 + tm + i;
        if (gm >= M) continue;
#pragma unroll
        for (int j = 0; j < 4; ++j) {
            int gn = n0 + tn + j;
            if (gn >= N) continue;
            float t = acc[i][j];
            if (bias) t += bias[gn];
            if (BNRELU) {
                float sc = g[gn] * rsqrtf(bv[gn] + BN_EPS);
                t = t * sc + (bb[gn] - bm[gn] * sc);
                t = fmaxf(t, 0.f);
            }
            C[(size_t)gm * N + gn] = t;
        }
    }
}

// ---------- C(M,8) = A(M,K) @ W(8,K)^T + bias ----------
__global__ __launch_bounds__(TPB) void gemm_n8(
    const float* __restrict__ A, const float* __restrict__ Wt,
    const float* __restrict__ bias, float* __restrict__ C, int M, int K)
{
    int idx = blockIdx.x * TPB + threadIdx.x;
    if (idx >= M * 8) return;
    int r = idx >> 3, j = idx & 7;
    const float4* a4 = (const float4*)(A + (size_t)r * K);
    const float4* w4 = (const float4*)(Wt + (size_t)j * K);
    float s = 0.f;
    int k4 = K >> 2;
    for (int k = 0; k < k4; ++k) {
        float4 av = a4[k], wv = w4[k];
        s += av.x * wv.x + av.y * wv.y + av.z * wv.z + av.w * wv.w;
    }
    if (bias) s += bias[j];
    C[idx] = s;
}

// ---------- per-node attention coefficients: el/er (N, HN) ----------
template<int HN, int DHD>
__global__ __launch_bounds__(TPB) void attn_coef_kernel(
    const float* __restrict__ feat, const float* __restrict__ al,
    const float* __restrict__ ar, float* __restrict__ el, float* __restrict__ er, int Nn)
{
    int idx = blockIdx.x * TPB + threadIdx.x;
    if (idx >= Nn * HN) return;
    int n = idx / HN, h = idx - n * HN;
    const float4* f4 = (const float4*)(feat + (size_t)n * (HN * DHD) + h * DHD);
    const float4* al4 = (const float4*)(al + h * DHD);
    const float4* ar4 = (const float4*)(ar + h * DHD);
    float sl = 0.f, sr = 0.f;
#pragma unroll
    for (int d = 0; d < DHD / 4; ++d) {
        float4 fv = f4[d], lv = al4[d], rv = ar4[d];
        sl += fv.x * lv.x + fv.y * lv.y + fv.z * lv.z + fv.w * lv.w;
        sr += fv.x * rv.x + fv.y * rv.y + fv.z * rv.z + fv.w * rv.w;
    }
    el[idx] = sl; er[idx] = sr;
}

// ================= CSR build (by dst) =================
__global__ __launch_bounds__(TPB) void hist_kernel(
    const int* __restrict__ dst, int* __restrict__ cnt, int E)
{
    int i = blockIdx.x * TPB + threadIdx.x;
    if (i >= E) return;
    atomicAdd(&cnt[dst[i]], 1);
}

// --- parallel scan, stage 1: per-block (1024 elems, 256 thr x 4) local inclusive scan ---
__global__ __launch_bounds__(256) void scan_local(
    const int* __restrict__ cnt, int* __restrict__ rowstart,
    int* __restrict__ blocksum, int Nn)
{
    __shared__ int wsum[4];
    int tid = threadIdx.x;
    int lane = tid & 63, wid = tid >> 6;
    int base = blockIdx.x * 1024 + tid * 4;
    int v0 = (base + 0 < Nn) ? cnt[base + 0] : 0;
    int v1 = (base + 1 < Nn) ? cnt[base + 1] : 0;
    int v2 = (base + 2 < Nn) ? cnt[base + 2] : 0;
    int v3 = (base + 3 < Nn) ? cnt[base + 3] : 0;
    int s1 = v0 + v1, s2 = s1 + v2, s3 = s2 + v3;
    // wave inclusive scan of per-thread sums
    int v = s3;
#pragma unroll
    for (int off = 1; off < 64; off <<= 1) {
        int t = __shfl_up(v, off, 64);
        if (lane >= off) v += t;
    }
    if (lane == 63) wsum[wid] = v;
    __syncthreads();
    int woff = 0;
#pragma unroll
    for (int w = 0; w < 4; ++w) woff += (w < wid) ? wsum[w] : 0;
    int excl = woff + v - s3;   // exclusive prefix for this thread's 4 elems
    if (base + 0 < Nn) rowstart[base + 1] = excl + v0;
    if (base + 1 < Nn) rowstart[base + 2] = excl + s1;
    if (base + 2 < Nn) rowstart[base + 3] = excl + s2;
    if (base + 3 < Nn) rowstart[base + 4] = excl + s3;
    if (tid == 255) blocksum[blockIdx.x] = woff + v;
}

// --- stage 2: exclusive scan of block sums (single wave; nblocks <= 64) ---
__global__ __launch_bounds__(64) void scan_blocks(
    const int* __restrict__ blocksum, int* __restrict__ blockoff, int nblocks)
{
    int lane = threadIdx.x;
    int v = (lane < nblocks) ? blocksum[lane] : 0;
#pragma unroll
    for (int off = 1; off < 64; off <<= 1) {
        int t = __shfl_up(v, off, 64);
        if (lane >= off) v += t;
    }
    if (lane < nblocks) blockoff[lane] = v - blocksum[lane];
}

// --- stage 3: add block offsets in place; also produce cursor (= exclusive scan) ---
__global__ __launch_bounds__(TPB) void add_offsets(
    int* __restrict__ rowstart, const int* __restrict__ blockoff,
    int* __restrict__ cursor, int Nn)
{
    int i = blockIdx.x * TPB + threadIdx.x;
    if (i >= Nn) return;
    int v = rowstart[i + 1] + blockoff[i >> 10];
    rowstart[i + 1] = v;
    if (i + 1 < Nn) cursor[i + 1] = v;
    if (i == 0) { rowstart[0] = 0; cursor[0] = 0; }
}

// scatter src node ids into CSR slots (order within a row is arbitrary — sum commutes)
__global__ __launch_bounds__(TPB) void scatter_kernel(
    const int* __restrict__ src, const int* __restrict__ dst,
    int* __restrict__ cursor, int* __restrict__ esrc, int E)
{
    int i = blockIdx.x * TPB + threadIdx.x;
    if (i >= E) return;
    int pos = atomicAdd(&cursor[dst[i]], 1);
    esrc[pos] = src[i];
}

// ========== GAT1 gather: one wave per dst node; fused softmax-denom + ELU + bias ==========
__global__ __launch_bounds__(TPB) void gat1_gather(
    const float* __restrict__ feat, const float* __restrict__ el,
    const float* __restrict__ er, const int* __restrict__ rowstart,
    const int* __restrict__ esrc, const float* __restrict__ bias,
    float* __restrict__ out, int Nn)
{
    int n = blockIdx.x * 4 + (threadIdx.x >> 6);
    if (n >= Nn) return;
    int lane = threadIdx.x & 63;
    int h = lane >> 4;
    int c = h * 64 + (lane & 15) * 4;
    float erv = er[n * 4 + h];
    int beg = rowstart[n], end = rowstart[n + 1];
    float4 acc = make_float4(0.f, 0.f, 0.f, 0.f);
    float dsum = 0.f;
    for (int e = beg; e < end; ++e) {
        int s = esrc[e];
        float ev = el[s * 4 + h] + erv;
        ev = ev > 0.f ? ev : 0.2f * ev;
        float av = __expf(ev);
        dsum += av;
        float4 fv = *(const float4*)(feat + (size_t)s * 256 + c);
        acc.x += av * fv.x; acc.y += av * fv.y; acc.z += av * fv.z; acc.w += av * fv.w;
    }
    float inv = 1.f / dsum;   // every node has a self-loop -> dsum > 0
    float4 bv = *(const float4*)(bias + c);
    float4 o;
    o.x = acc.x * inv + bv.x; o.y = acc.y * inv + bv.y;
    o.z = acc.z * inv + bv.z; o.w = acc.w * inv + bv.w;
    o.x = o.x > 0.f ? o.x : __expf(o.x) - 1.f;
    o.y = o.y > 0.f ? o.y : __expf(o.y) - 1.f;
    o.z = o.z > 0.f ? o.z : __expf(o.z) - 1.f;
    o.w = o.w > 0.f ? o.w : __expf(o.w) - 1.f;
    *(float4*)(out + (size_t)n * 256 + c) = o;
}

// ========== GAT2 gather: 8 threads per dst node ==========
__global__ __launch_bounds__(TPB) void gat2_gather(
    const float* __restrict__ feat2, const float* __restrict__ el,
    const float* __restrict__ er, const int* __restrict__ rowstart,
    const int* __restrict__ esrc, float* __restrict__ out2, int Nn)
{
    int idx = blockIdx.x * TPB + threadIdx.x;
    if (idx >= Nn * 8) return;
    int n = idx >> 3, j = idx & 7;
    float erv = er[n];
    int beg = rowstart[n], end = rowstart[n + 1];
    float acc = 0.f, dsum = 0.f;
    for (int e = beg; e < end; ++e) {
        int s = esrc[e];
        float ev = el[s] + erv;
        ev = ev > 0.f ? ev : 0.2f * ev;
        float av = __expf(ev);
        dsum += av;
        acc += av * feat2[(size_t)s * 8 + j];
    }
    out2[idx] = acc / dsum;
}

// ---------- gates + combine + output GEMM + softmax ----------
__global__ __launch_bounds__(TPB) void final_kernel(
    const float* __restrict__ wide, const float* __restrict__ deep,
    const float* __restrict__ out2, const int* __restrict__ Xid,
    const float* __restrict__ g2bias,
    const float* __restrict__ g1w, const float* __restrict__ g1b,
    const float* __restrict__ g2w, const float* __restrict__ g2b,
    const float* __restrict__ g3w, const float* __restrict__ g3b,
    const float* __restrict__ goutw, const float* __restrict__ goutb,
    float* __restrict__ out, int B)
{
    int b = blockIdx.x * TPB + threadIdx.x;
    if (b >= B) return;
    float w8[8], d8[8], g8[8];
    {
        float4 t0 = *(const float4*)(wide + (size_t)b * 8);
        float4 t1 = *(const float4*)(wide + (size_t)b * 8 + 4);
        w8[0] = t0.x; w8[1] = t0.y; w8[2] = t0.z; w8[3] = t0.w;
        w8[4] = t1.x; w8[5] = t1.y; w8[6] = t1.z; w8[7] = t1.w;
        t0 = *(const float4*)(deep + (size_t)b * 8);
        t1 = *(const float4*)(deep + (size_t)b * 8 + 4);
        d8[0] = t0.x; d8[1] = t0.y; d8[2] = t0.z; d8[3] = t0.w;
        d8[4] = t1.x; d8[5] = t1.y; d8[6] = t1.z; d8[7] = t1.w;
    }
    int commit = Xid[b * 2 + 1];
#pragma unroll
    for (int j = 0; j < 8; ++j) g8[j] = out2[(size_t)commit * 8 + j] + g2bias[j];
    float s1 = g1b[0], s2 = g2b[0], s3 = g3b[0];
#pragma unroll
    for (int j = 0; j < 8; ++j) { s1 += w8[j] * g1w[j]; s2 += d8[j] * g2w[j]; s3 += g8[j] * g3w[j]; }
    float aw = sigmoidf_(s1), bw = sigmoidf_(s2), cw = sigmoidf_(s3);
    float inv_tot = 1.f / (aw + bw + cw);
    float an = aw * inv_tot, bn = bw * inv_tot, cn = cw * inv_tot;
    float o0 = goutb[0], o1 = goutb[1];
#pragma unroll
    for (int j = 0; j < 8; ++j) {
        float c0 = an * w8[j]; o0 += goutw[j] * c0;      o1 += goutw[24 + j] * c0;
        float c1 = bn * d8[j]; o0 += goutw[8 + j] * c1;  o1 += goutw[32 + j] * c1;
        float c2 = cn * g8[j]; o0 += goutw[16 + j] * c2; o1 += goutw[40 + j] * c2;
    }
    float mx = fmaxf(o0, o1);
    float e0 = __expf(o0 - mx), e1 = __expf(o1 - mx);
    float inv = 1.f / (e0 + e1);
    out[(size_t)b * 2] = e0 * inv;
    out[(size_t)b * 2 + 1] = e1 * inv;
}

extern "C" void kernel_launch(void* const* d_in, const int* in_sizes, int n_in,
                              void* d_out, int out_size, void* d_ws, size_t ws_size,
                              hipStream_t stream)
{
    const int*   Xid    = (const int*)d_in[0];
    const int*   Xs     = (const int*)d_in[1];
    const float* Xd     = (const float*)d_in[2];
    const float* emb    = (const float*)d_in[3];
    const float* gfeat  = (const float*)d_in[4];
    const int*   src    = (const int*)d_in[5];
    const int*   dst    = (const int*)d_in[6];
    const float* wide_w = (const float*)d_in[7];
    const float* wide_b = (const float*)d_in[8];
    const float* lin1_w = (const float*)d_in[9];
    const float* lin1_b = (const float*)d_in[10];
    const float* bn1_g  = (const float*)d_in[11];
    const float* bn1_b  = (const float*)d_in[12];
    const float* bn1_m  = (const float*)d_in[13];
    const float* bn1_v  = (const float*)d_in[14];
    const float* lin2_w = (const float*)d_in[15];
    const float* lin2_b = (const float*)d_in[16];
    const float* bn2_g  = (const float*)d_in[17];
    const float* bn2_b  = (const float*)d_in[18];
    const float* bn2_m  = (const float*)d_in[19];
    const float* bn2_v  = (const float*)d_in[20];
    const float* dnn_w  = (const float*)d_in[21];
    const float* dnn_b  = (const float*)d_in[22];
    const float* gat1_w = (const float*)d_in[23];
    const float* gat1_al = (const float*)d_in[24];
    const float* gat1_ar = (const float*)d_in[25];
    const float* gat1_bias = (const float*)d_in[26];
    const float* gat2_w = (const float*)d_in[27];
    const float* gat2_al = (const float*)d_in[28];
    const float* gat2_ar = (const float*)d_in[29];
    const float* gat2_bias = (const float*)d_in[30];
    const float* g1w = (const float*)d_in[31];
    const float* g1b = (const float*)d_in[32];
    const float* g2w = (const float*)d_in[33];
    const float* g2b = (const float*)d_in[34];
    const float* g3w = (const float*)d_in[35];
    const float* g3b = (const float*)d_in[36];
    const float* goutw = (const float*)d_in[37];
    const float* goutb = (const float*)d_in[38];

    const int B    = in_sizes[0] / 2;     // 16384
    const int Nn   = in_sizes[4] / 128;   // 50000
    const int Etot = in_sizes[5];         // 450000

    // ---- workspace layout (floats); deep-path x/d1/d2 alias under out1 ----
    float* ws    = (float*)d_ws;
    float* xb    = ws;                         // B*224   (aliases out1)
    float* d1    = xb + (size_t)B * 224;       // B*256
    float* d2    = d1 + (size_t)B * 256;       // B*256   (ends at 12.06M < Nn*256)
    float* out1  = ws;                         // Nn*256  (written by gat1_gather, all rows)
    float* feat1 = ws + (size_t)Nn * 256;      // Nn*256
    float* wide  = feat1 + (size_t)Nn * 256;   // B*8
    float* deep  = wide + (size_t)B * 8;       // B*8
    float* el1   = deep + (size_t)B * 8;       // Nn*4
    float* er1   = el1 + (size_t)Nn * 4;       // Nn*4
    float* feat2 = er1 + (size_t)Nn * 4;       // Nn*8
    float* el2   = feat2 + (size_t)Nn * 8;     // Nn
    float* er2   = el2 + Nn;                   // Nn
    float* out2  = er2 + Nn;                   // Nn*8
    int* rowstart = (int*)(out2 + (size_t)Nn * 8);  // Nn+1
    int* cnt      = rowstart + (Nn + 1);            // Nn+1
    int* cursor   = cnt + (Nn + 1);                 // Nn
    int* esrc     = cursor + Nn;                    // Etot
    int* blocksum = esrc + Etot;                    // 64
    int* blockoff = blocksum + 64;                  // 64

    const int nScanBlocks = (Nn + 1023) / 1024;     // 49 (<= 64 for single-wave stage 2)

    // ---- CSR build (shared by both GAT layers) ----
    hipMemsetAsync(cnt, 0, (size_t)(Nn + 1) * sizeof(int), stream);
    hist_kernel<<<(Etot + TPB - 1) / TPB, TPB, 0, stream>>>(dst, cnt, Etot);
    scan_local<<<nScanBlocks, 256, 0, stream>>>(cnt, rowstart, blocksum, Nn);
    scan_blocks<<<1, 64, 0, stream>>>(blocksum, blockoff, nScanBlocks);
    add_offsets<<<(Nn + TPB - 1) / TPB, TPB, 0, stream>>>(rowstart, blockoff, cursor, Nn);
    scatter_kernel<<<(Etot + TPB - 1) / TPB, TPB, 0, stream>>>(src, dst, cursor, esrc, Etot);

    // ---- deep path (uses the region aliased under out1; must finish before gat1_gather) ----
    build_x_kernel<<<(B * 224 + TPB - 1) / TPB, TPB, 0, stream>>>(Xs, Xd, emb, xb, B);
    gemm_nt<true><<<dim3((B + 63) / 64, 4), 256, 0, stream>>>(
        xb, lin1_w, lin1_b, bn1_g, bn1_b, bn1_m, bn1_v, d1, B, 256, 224);
    gemm_nt<true><<<dim3((B + 63) / 64, 4), 256, 0, stream>>>(
        d1, lin2_w, lin2_b, bn2_g, bn2_b, bn2_m, bn2_v, d2, B, 256, 256);
    gemm_n8<<<(B * 8 + TPB - 1) / TPB, TPB, 0, stream>>>(Xd, wide_w, wide_b, wide, B, 64);
    gemm_n8<<<(B * 8 + TPB - 1) / TPB, TPB, 0, stream>>>(d2, dnn_w, dnn_b, deep, B, 256);

    // ---- GAT layer 1 ----
    gemm_nt<false><<<dim3((Nn + 63) / 64, 4), 256, 0, stream>>>(
        gfeat, gat1_w, nullptr, nullptr, nullptr, nullptr, nullptr, feat1, Nn, 256, 128);
    attn_coef_kernel<4, 64><<<(Nn * 4 + TPB - 1) / TPB, TPB, 0, stream>>>(
        feat1, gat1_al, gat1_ar, el1, er1, Nn);
    gat1_gather<<<(Nn + 3) / 4, TPB, 0, stream>>>(
        feat1, el1, er1, rowstart, esrc, gat1_bias, out1, Nn);

    // ---- GAT layer 2 ----
    gemm_n8<<<(Nn * 8 + TPB - 1) / TPB, TPB, 0, stream>>>(out1, gat2_w, nullptr, feat2, Nn, 256);
    attn_coef_kernel<1, 8><<<(Nn + TPB - 1) / TPB, TPB, 0, stream>>>(
        feat2, gat2_al, gat2_ar, el2, er2, Nn);
    gat2_gather<<<(Nn * 8 + TPB - 1) / TPB, TPB, 0, stream>>>(
        feat2, el2, er2, rowstart, esrc, out2, Nn);

    // ---- gates + output ----
    final_kernel<<<(B + TPB - 1) / TPB, TPB, 0, stream>>>(
        wide, deep, out2, Xid, gat2_bias, g1w, g1b, g2w, g2b, g3w, g3b, goutw, goutb,
        (float*)d_out, B);
}

// Round 5
// 450.656 us; speedup vs baseline: 4.4613x; 1.2086x over previous
//
#include <hip/hip_runtime.h>

#define TPB 256
constexpr float BN_EPS = 1e-5f;

typedef __attribute__((ext_vector_type(8))) short short8;
typedef __attribute__((ext_vector_type(4))) float floatx4;

__device__ __forceinline__ float sigmoidf_(float x) { return 1.f / (1.f + __expf(-x)); }
__device__ __forceinline__ unsigned short f2bf(float f) {   // RTNE
    unsigned u = __float_as_uint(f);
    u += 0x7FFFu + ((u >> 16) & 1u);
    return (unsigned short)(u >> 16);
}
__device__ __forceinline__ float bf2f(unsigned short h) {
    return __uint_as_float((unsigned)h << 16);
}

// ---------- fp32 -> bf16 converters ----------
__global__ __launch_bounds__(TPB) void f32_to_bf16_vec(
    const float* __restrict__ in, unsigned short* __restrict__ out, int n4)
{
    int i = blockIdx.x * TPB + threadIdx.x;
    if (i >= n4) return;
    float4 v = ((const float4*)in)[i];
    ushort4 o;
    o.x = f2bf(v.x); o.y = f2bf(v.y); o.z = f2bf(v.z); o.w = f2bf(v.w);
    ((ushort4*)out)[i] = o;
}

__global__ __launch_bounds__(TPB) void convert3_kernel(
    const float* __restrict__ w1, unsigned short* __restrict__ o1, int n1,
    const float* __restrict__ w2, unsigned short* __restrict__ o2, int n2,
    const float* __restrict__ w3, unsigned short* __restrict__ o3, int n3)
{
    int i = blockIdx.x * TPB + threadIdx.x;
    if (i < n1) o1[i] = f2bf(w1[i]);
    else if (i < n1 + n2) o2[i - n1] = f2bf(w2[i - n1]);
    else if (i < n1 + n2 + n3) o3[i - n1 - n2] = f2bf(w3[i - n1 - n2]);
}

// ---------- build x = [sparse_embed (20*8) | dense (64)] : (B, 224) bf16 ----------
__global__ __launch_bounds__(TPB) void build_x_kernel(
    const int* __restrict__ Xs, const float* __restrict__ Xd,
    const float* __restrict__ emb, unsigned short* __restrict__ x, int B)
{
    int idx = blockIdx.x * TPB + threadIdx.x;
    if (idx >= B * 224) return;
    int b = idx / 224, c = idx - b * 224;
    float v;
    if (c < 160) {
        int s = c >> 3, j = c & 7;
        int e = Xs[b * 20 + s];
        v = emb[((size_t)s * 1000 + e) * 8 + j];
    } else {
        v = Xd[b * 64 + (c - 160)];
    }
    x[idx] = f2bf(v);
}

// ---------- bf16 MFMA GEMM: C(M,N)bf16 = A(M,K)bf16 @ W(N,K)bf16^T (+bias+bn+relu) ----------
// 128x128 tile, 4 waves 2x2, each wave 4x4 of mfma_f32_16x16x32_bf16.
// One MFMA per (i,j) per 32-wide K-tile: lane's 8 elems cover k = (lane>>4)*8 + j, j<8
// (the full K=32 of the instruction). A-frag m = lane&15; C/D col=lane&15, row=(lane>>4)*4+reg.
template<bool BNRELU>
__global__ __launch_bounds__(256) void gemm_mfma(
    const unsigned short* __restrict__ A, const unsigned short* __restrict__ W,
    const float* __restrict__ bias,
    const float* __restrict__ g, const float* __restrict__ bb,
    const float* __restrict__ bm, const float* __restrict__ bv,
    unsigned short* __restrict__ C, int M, int N, int K)
{
    constexpr int SK = 40;   // padded LDS stride (bf16): row byte-stride 80 -> 16B aligned, 2-way bank max (free)
    __shared__ unsigned short As[128 * SK];
    __shared__ unsigned short Bs[128 * SK];
    int tid = threadIdx.x;
    int wave = tid >> 6, lane = tid & 63;
    int wm = (wave & 1) * 64, wn = (wave >> 1) * 64;
    int m0 = blockIdx.x * 128, n0 = blockIdx.y * 128;
    int lrow = lane & 15, lk = (lane >> 4) * 8;
    floatx4 acc[4][4] = {};
    for (int k0 = 0; k0 < K; k0 += 32) {
#pragma unroll
        for (int i = 0; i < 2; ++i) {
            int idx = tid + i * 256;              // 0..511 -> 128 rows x 4 segs of 8 bf16
            int r = idx >> 2, seg = (idx & 3) * 8;
            uint4 av = make_uint4(0u, 0u, 0u, 0u);
            int gm = m0 + r;
            if (gm < M) av = *(const uint4*)(A + (size_t)gm * K + k0 + seg);
            *(uint4*)(As + r * SK + seg) = av;
            uint4 wv = make_uint4(0u, 0u, 0u, 0u);
            int gn = n0 + r;
            if (gn < N) wv = *(const uint4*)(W + (size_t)gn * K + k0 + seg);
            *(uint4*)(Bs + r * SK + seg) = wv;
        }
        __syncthreads();
        short8 af[4], bfr[4];
#pragma unroll
        for (int i = 0; i < 4; ++i)
            af[i] = *(const short8*)(As + (wm + i * 16 + lrow) * SK + lk);
#pragma unroll
        for (int j = 0; j < 4; ++j)
            bfr[j] = *(const short8*)(Bs + (wn + j * 16 + lrow) * SK + lk);
#pragma unroll
        for (int i = 0; i < 4; ++i)
#pragma unroll
            for (int j = 0; j < 4; ++j)
                acc[i][j] = __builtin_amdgcn_mfma_f32_16x16x32_bf16(
                    af[i], bfr[j], acc[i][j], 0, 0, 0);
        __syncthreads();
    }
    int crow = (lane >> 4) * 4, ccol = lane & 15;
#pragma unroll
    for (int j = 0; j < 4; ++j) {
        int gn = n0 + wn + j * 16 + ccol;
        float sc = 1.f, sh = 0.f;
        if (BNRELU) {
            sc = g[gn] * rsqrtf(bv[gn] + BN_EPS);
            sh = (bias[gn] - bm[gn]) * sc + bb[gn];   // t = (acc+bias-m)*sc + bb
        }
#pragma unroll
        for (int i = 0; i < 4; ++i) {
#pragma unroll
            for (int r = 0; r < 4; ++r) {
                int gm = m0 + wm + i * 16 + crow + r;
                if (gm >= M) continue;
                float t = acc[i][j][r];
                if (BNRELU) t = fmaxf(t * sc + sh, 0.f);
                C[(size_t)gm * N + gn] = f2bf(t);
            }
        }
    }
}

// ---------- C(M,8)fp32 = A(M,K)fp32 @ W(8,K)^T + bias ----------
__global__ __launch_bounds__(TPB) void gemm_n8(
    const float* __restrict__ A, const float* __restrict__ Wt,
    const float* __restrict__ bias, float* __restrict__ C, int M, int K)
{
    int idx = blockIdx.x * TPB + threadIdx.x;
    if (idx >= M * 8) return;
    int r = idx >> 3, j = idx & 7;
    const float4* a4 = (const float4*)(A + (size_t)r * K);
    const float4* w4 = (const float4*)(Wt + (size_t)j * K);
    float s = 0.f;
    int k4 = K >> 2;
    for (int k = 0; k < k4; ++k) {
        float4 av = a4[k], wv = w4[k];
        s += av.x * wv.x + av.y * wv.y + av.z * wv.z + av.w * wv.w;
    }
    if (bias) s += bias[j];
    C[idx] = s;
}

// ---------- C(M,8)fp32 = A(M,K)bf16 @ W(8,K)fp32^T + bias ----------
__global__ __launch_bounds__(TPB) void gemm_n8_bf16(
    const unsigned short* __restrict__ A, const float* __restrict__ Wt,
    const float* __restrict__ bias, float* __restrict__ C, int M, int K)
{
    int idx = blockIdx.x * TPB + threadIdx.x;
    if (idx >= M * 8) return;
    int r = idx >> 3, j = idx & 7;
    const uint2* a4 = (const uint2*)(A + (size_t)r * K);
    const float4* w4 = (const float4*)(Wt + (size_t)j * K);
    float s = 0.f;
    int k4 = K >> 2;
    for (int k = 0; k < k4; ++k) {
        uint2 ab = a4[k];
        float4 wv = w4[k];
        s += bf2f((unsigned short)(ab.x & 0xFFFFu)) * wv.x
           + bf2f((unsigned short)(ab.x >> 16)) * wv.y
           + bf2f((unsigned short)(ab.y & 0xFFFFu)) * wv.z
           + bf2f((unsigned short)(ab.y >> 16)) * wv.w;
    }
    if (bias) s += bias[j];
    C[idx] = s;
}

// ---------- per-node attention coefficients (bf16 feat): el/er (N, HN) ----------
template<int HN, int DHD>
__global__ __launch_bounds__(TPB) void attn_coef_bf16(
    const unsigned short* __restrict__ feat, const float* __restrict__ al,
    const float* __restrict__ ar, float* __restrict__ el, float* __restrict__ er, int Nn)
{
    int idx = blockIdx.x * TPB + threadIdx.x;
    if (idx >= Nn * HN) return;
    int n = idx / HN, h = idx - n * HN;
    const uint2* f4 = (const uint2*)(feat + (size_t)n * (HN * DHD) + h * DHD);
    const float4* al4 = (const float4*)(al + h * DHD);
    const float4* ar4 = (const float4*)(ar + h * DHD);
    float sl = 0.f, sr = 0.f;
#pragma unroll
    for (int d = 0; d < DHD / 4; ++d) {
        uint2 fb = f4[d];
        float f0 = bf2f((unsigned short)(fb.x & 0xFFFFu));
        float f1 = bf2f((unsigned short)(fb.x >> 16));
        float f2 = bf2f((unsigned short)(fb.y & 0xFFFFu));
        float f3 = bf2f((unsigned short)(fb.y >> 16));
        float4 lv = al4[d], rv = ar4[d];
        sl += f0 * lv.x + f1 * lv.y + f2 * lv.z + f3 * lv.w;
        sr += f0 * rv.x + f1 * rv.y + f2 * rv.z + f3 * rv.w;
    }
    el[idx] = sl; er[idx] = sr;
}

// ---------- per-node attention coefficients (fp32 feat): GAT2 ----------
template<int HN, int DHD>
__global__ __launch_bounds__(TPB) void attn_coef_kernel(
    const float* __restrict__ feat, const float* __restrict__ al,
    const float* __restrict__ ar, float* __restrict__ el, float* __restrict__ er, int Nn)
{
    int idx = blockIdx.x * TPB + threadIdx.x;
    if (idx >= Nn * HN) return;
    int n = idx / HN, h = idx - n * HN;
    const float4* f4 = (const float4*)(feat + (size_t)n * (HN * DHD) + h * DHD);
    const float4* al4 = (const float4*)(al + h * DHD);
    const float4* ar4 = (const float4*)(ar + h * DHD);
    float sl = 0.f, sr = 0.f;
#pragma unroll
    for (int d = 0; d < DHD / 4; ++d) {
        float4 fv = f4[d], lv = al4[d], rv = ar4[d];
        sl += fv.x * lv.x + fv.y * lv.y + fv.z * lv.z + fv.w * lv.w;
        sr += fv.x * rv.x + fv.y * rv.y + fv.z * rv.z + fv.w * rv.w;
    }
    el[idx] = sl; er[idx] = sr;
}

// ================= CSR build (by dst) =================
__global__ __launch_bounds__(TPB) void hist_kernel(
    const int* __restrict__ dst, int* __restrict__ cnt, int E)
{
    int i = blockIdx.x * TPB + threadIdx.x;
    if (i >= E) return;
    atomicAdd(&cnt[dst[i]], 1);
}

__global__ __launch_bounds__(256) void scan_local(
    const int* __restrict__ cnt, int* __restrict__ rowstart,
    int* __restrict__ blocksum, int Nn)
{
    __shared__ int wsum[4];
    int tid = threadIdx.x;
    int lane = tid & 63, wid = tid >> 6;
    int base = blockIdx.x * 1024 + tid * 4;
    int v0 = (base + 0 < Nn) ? cnt[base + 0] : 0;
    int v1 = (base + 1 < Nn) ? cnt[base + 1] : 0;
    int v2 = (base + 2 < Nn) ? cnt[base + 2] : 0;
    int v3 = (base + 3 < Nn) ? cnt[base + 3] : 0;
    int s1 = v0 + v1, s2 = s1 + v2, s3 = s2 + v3;
    int v = s3;
#pragma unroll
    for (int off = 1; off < 64; off <<= 1) {
        int t = __shfl_up(v, off, 64);
        if (lane >= off) v += t;
    }
    if (lane == 63) wsum[wid] = v;
    __syncthreads();
    int woff = 0;
#pragma unroll
    for (int w = 0; w < 4; ++w) woff += (w < wid) ? wsum[w] : 0;
    int excl = woff + v - s3;
    if (base + 0 < Nn) rowstart[base + 1] = excl + v0;
    if (base + 1 < Nn) rowstart[base + 2] = excl + s1;
    if (base + 2 < Nn) rowstart[base + 3] = excl + s2;
    if (base + 3 < Nn) rowstart[base + 4] = excl + s3;
    if (tid == 255) blocksum[blockIdx.x] = woff + v;
}

__global__ __launch_bounds__(64) void scan_blocks(
    const int* __restrict__ blocksum, int* __restrict__ blockoff, int nblocks)
{
    int lane = threadIdx.x;
    int v = (lane < nblocks) ? blocksum[lane] : 0;
#pragma unroll
    for (int off = 1; off < 64; off <<= 1) {
        int t = __shfl_up(v, off, 64);
        if (lane >= off) v += t;
    }
    if (lane < nblocks) blockoff[lane] = v - blocksum[lane];
}

__global__ __launch_bounds__(TPB) void add_offsets(
    int* __restrict__ rowstart, const int* __restrict__ blockoff,
    int* __restrict__ cursor, int Nn)
{
    int i = blockIdx.x * TPB + threadIdx.x;
    if (i >= Nn) return;
    int v = rowstart[i + 1] + blockoff[i >> 10];
    rowstart[i + 1] = v;
    if (i + 1 < Nn) cursor[i + 1] = v;
    if (i == 0) { rowstart[0] = 0; cursor[0] = 0; }
}

__global__ __launch_bounds__(TPB) void scatter_kernel(
    const int* __restrict__ src, const int* __restrict__ dst,
    int* __restrict__ cursor, int* __restrict__ esrc, int E)
{
    int i = blockIdx.x * TPB + threadIdx.x;
    if (i >= E) return;
    int pos = atomicAdd(&cursor[dst[i]], 1);
    esrc[pos] = src[i];
}

// ========== GAT1 gather (bf16 feat): one wave per dst; fused softmax + ELU + bias ==========
__global__ __launch_bounds__(TPB) void gat1_gather(
    const unsigned short* __restrict__ feat, const float* __restrict__ el,
    const float* __restrict__ er, const int* __restrict__ rowstart,
    const int* __restrict__ esrc, const float* __restrict__ bias,
    float* __restrict__ out, int Nn)
{
    int n = blockIdx.x * 4 + (threadIdx.x >> 6);
    if (n >= Nn) return;
    int lane = threadIdx.x & 63;
    int h = lane >> 4;
    int c = h * 64 + (lane & 15) * 4;   // 4 columns of the 256-wide row (8B bf16, aligned)
    float erv = er[n * 4 + h];
    int beg = rowstart[n], end = rowstart[n + 1];
    float4 acc = make_float4(0.f, 0.f, 0.f, 0.f);
    float dsum = 0.f;
    for (int e = beg; e < end; ++e) {
        int s = esrc[e];
        float ev = el[s * 4 + h] + erv;
        ev = ev > 0.f ? ev : 0.2f * ev;
        float av = __expf(ev);
        dsum += av;
        uint2 fb = *(const uint2*)(feat + (size_t)s * 256 + c);
        acc.x += av * bf2f((unsigned short)(fb.x & 0xFFFFu));
        acc.y += av * bf2f((unsigned short)(fb.x >> 16));
        acc.z += av * bf2f((unsigned short)(fb.y & 0xFFFFu));
        acc.w += av * bf2f((unsigned short)(fb.y >> 16));
    }
    float inv = 1.f / dsum;   // self-loop guarantees dsum > 0
    float4 bv = *(const float4*)(bias + c);
    float4 o;
    o.x = acc.x * inv + bv.x; o.y = acc.y * inv + bv.y;
    o.z = acc.z * inv + bv.z; o.w = acc.w * inv + bv.w;
    o.x = o.x > 0.f ? o.x : __expf(o.x) - 1.f;
    o.y = o.y > 0.f ? o.y : __expf(o.y) - 1.f;
    o.z = o.z > 0.f ? o.z : __expf(o.z) - 1.f;
    o.w = o.w > 0.f ? o.w : __expf(o.w) - 1.f;
    *(float4*)(out + (size_t)n * 256 + c) = o;
}

// ========== GAT2 gather: 8 threads per dst node ==========
__global__ __launch_bounds__(TPB) void gat2_gather(
    const float* __restrict__ feat2, const float* __restrict__ el,
    const float* __restrict__ er, const int* __restrict__ rowstart,
    const int* __restrict__ esrc, float* __restrict__ out2, int Nn)
{
    int idx = blockIdx.x * TPB + threadIdx.x;
    if (idx >= Nn * 8) return;
    int n = idx >> 3, j = idx & 7;
    float erv = er[n];
    int beg = rowstart[n], end = rowstart[n + 1];
    float acc = 0.f, dsum = 0.f;
    for (int e = beg; e < end; ++e) {
        int s = esrc[e];
        float ev = el[s] + erv;
        ev = ev > 0.f ? ev : 0.2f * ev;
        float av = __expf(ev);
        dsum += av;
        acc += av * feat2[(size_t)s * 8 + j];
    }
    out2[idx] = acc / dsum;
}

// ---------- gates + combine + output GEMM + softmax ----------
__global__ __launch_bounds__(TPB) void final_kernel(
    const float* __restrict__ wide, const float* __restrict__ deep,
    const float* __restrict__ out2, const int* __restrict__ Xid,
    const float* __restrict__ g2bias,
    const float* __restrict__ g1w, const float* __restrict__ g1b,
    const float* __restrict__ g2w, const float* __restrict__ g2b,
    const float* __restrict__ g3w, const float* __restrict__ g3b,
    const float* __restrict__ goutw, const float* __restrict__ goutb,
    float* __restrict__ out, int B)
{
    int b = blockIdx.x * TPB + threadIdx.x;
    if (b >= B) return;
    float w8[8], d8[8], g8[8];
    {
        float4 t0 = *(const float4*)(wide + (size_t)b * 8);
        float4 t1 = *(const float4*)(wide + (size_t)b * 8 + 4);
        w8[0] = t0.x; w8[1] = t0.y; w8[2] = t0.z; w8[3] = t0.w;
        w8[4] = t1.x; w8[5] = t1.y; w8[6] = t1.z; w8[7] = t1.w;
        t0 = *(const float4*)(deep + (size_t)b * 8);
        t1 = *(const float4*)(deep + (size_t)b * 8 + 4);
        d8[0] = t0.x; d8[1] = t0.y; d8[2] = t0.z; d8[3] = t0.w;
        d8[4] = t1.x; d8[5] = t1.y; d8[6] = t1.z; d8[7] = t1.w;
    }
    int commit = Xid[b * 2 + 1];
#pragma unroll
    for (int j = 0; j < 8; ++j) g8[j] = out2[(size_t)commit * 8 + j] + g2bias[j];
    float s1 = g1b[0], s2 = g2b[0], s3 = g3b[0];
#pragma unroll
    for (int j = 0; j < 8; ++j) { s1 += w8[j] * g1w[j]; s2 += d8[j] * g2w[j]; s3 += g8[j] * g3w[j]; }
    float aw = sigmoidf_(s1), bw = sigmoidf_(s2), cw = sigmoidf_(s3);
    float inv_tot = 1.f / (aw + bw + cw);
    float an = aw * inv_tot, bn = bw * inv_tot, cn = cw * inv_tot;
    float o0 = goutb[0], o1 = goutb[1];
#pragma unroll
    for (int j = 0; j < 8; ++j) {
        float c0 = an * w8[j]; o0 += goutw[j] * c0;      o1 += goutw[24 + j] * c0;
        float c1 = bn * d8[j]; o0 += goutw[8 + j] * c1;  o1 += goutw[32 + j] * c1;
        float c2 = cn * g8[j]; o0 += goutw[16 + j] * c2; o1 += goutw[40 + j] * c2;
    }
    float mx = fmaxf(o0, o1);
    float e0 = __expf(o0 - mx), e1 = __expf(o1 - mx);
    float inv = 1.f / (e0 + e1);
    out[(size_t)b * 2] = e0 * inv;
    out[(size_t)b * 2 + 1] = e1 * inv;
}

extern "C" void kernel_launch(void* const* d_in, const int* in_sizes, int n_in,
                              void* d_out, int out_size, void* d_ws, size_t ws_size,
                              hipStream_t stream)
{
    const int*   Xid    = (const int*)d_in[0];
    const int*   Xs     = (const int*)d_in[1];
    const float* Xd     = (const float*)d_in[2];
    const float* emb    = (const float*)d_in[3];
    const float* gfeat  = (const float*)d_in[4];
    const int*   src    = (const int*)d_in[5];
    const int*   dst    = (const int*)d_in[6];
    const float* wide_w = (const float*)d_in[7];
    const float* wide_b = (const float*)d_in[8];
    const float* lin1_w = (const float*)d_in[9];
    const float* lin1_b = (const float*)d_in[10];
    const float* bn1_g  = (const float*)d_in[11];
    const float* bn1_b  = (const float*)d_in[12];
    const float* bn1_m  = (const float*)d_in[13];
    const float* bn1_v  = (const float*)d_in[14];
    const float* lin2_w = (const float*)d_in[15];
    const float* lin2_b = (const float*)d_in[16];
    const float* bn2_g  = (const float*)d_in[17];
    const float* bn2_b  = (const float*)d_in[18];
    const float* bn2_m  = (const float*)d_in[19];
    const float* bn2_v  = (const float*)d_in[20];
    const float* dnn_w  = (const float*)d_in[21];
    const float* dnn_b  = (const float*)d_in[22];
    const float* gat1_w = (const float*)d_in[23];
    const float* gat1_al = (const float*)d_in[24];
    const float* gat1_ar = (const float*)d_in[25];
    const float* gat1_bias = (const float*)d_in[26];
    const float* gat2_w = (const float*)d_in[27];
    const float* gat2_al = (const float*)d_in[28];
    const float* gat2_ar = (const float*)d_in[29];
    const float* gat2_bias = (const float*)d_in[30];
    const float* g1w = (const float*)d_in[31];
    const float* g1b = (const float*)d_in[32];
    const float* g2w = (const float*)d_in[33];
    const float* g2b = (const float*)d_in[34];
    const float* g3w = (const float*)d_in[35];
    const float* g3b = (const float*)d_in[36];
    const float* goutw = (const float*)d_in[37];
    const float* goutb = (const float*)d_in[38];

    const int B    = in_sizes[0] / 2;     // 16384
    const int Nn   = in_sizes[4] / 128;   // 50000
    const int Etot = in_sizes[5];         // 450000

    // ---- workspace layout (bytes, 256-aligned). Deep-path bf16 bufs alias under out1 ----
    char* base = (char*)d_ws;
    size_t off = 0;
    auto alloc = [&](size_t bytes) -> char* {
        char* p = base + off;
        off += (bytes + 255) & ~(size_t)255;
        return p;
    };
    float* out1 = (float*)alloc((size_t)Nn * 256 * 4);       // 51.2 MB, region 0
    // aliased inside region 0 (deep path retires before gat1_gather writes out1):
    unsigned short* xb = (unsigned short*)base;                          // B*224*2 = 7.34 MB
    unsigned short* d1 = (unsigned short*)(base + 7340032);              // B*256*2 = 8.39 MB
    unsigned short* d2 = (unsigned short*)(base + 7340032 + 8388608);    // ends at 24.1 MB < 51.2 MB
    unsigned short* feat1  = (unsigned short*)alloc((size_t)Nn * 256 * 2);
    unsigned short* gfeatb = (unsigned short*)alloc((size_t)Nn * 128 * 2);
    unsigned short* w1b = (unsigned short*)alloc(256 * 224 * 2);
    unsigned short* w2b = (unsigned short*)alloc(256 * 256 * 2);
    unsigned short* wg1b = (unsigned short*)alloc(256 * 128 * 2);
    float* wide  = (float*)alloc((size_t)B * 8 * 4);
    float* deep  = (float*)alloc((size_t)B * 8 * 4);
    float* el1   = (float*)alloc((size_t)Nn * 4 * 4);
    float* er1   = (float*)alloc((size_t)Nn * 4 * 4);
    float* feat2 = (float*)alloc((size_t)Nn * 8 * 4);
    float* el2   = (float*)alloc((size_t)Nn * 4);
    float* er2   = (float*)alloc((size_t)Nn * 4);
    float* out2  = (float*)alloc((size_t)Nn * 8 * 4);
    int* rowstart = (int*)alloc((size_t)(Nn + 1) * 4);
    int* cnt      = (int*)alloc((size_t)(Nn + 1) * 4);
    int* cursor   = (int*)alloc((size_t)Nn * 4);
    int* esrc     = (int*)alloc((size_t)Etot * 4);
    int* blocksum = (int*)alloc(64 * 4);
    int* blockoff = (int*)alloc(64 * 4);

    const int nScanBlocks = (Nn + 1023) / 1024;   // 49 <= 64

    // ---- CSR build ----
    hipMemsetAsync(cnt, 0, (size_t)(Nn + 1) * sizeof(int), stream);
    hist_kernel<<<(Etot + TPB - 1) / TPB, TPB, 0, stream>>>(dst, cnt, Etot);
    scan_local<<<nScanBlocks, 256, 0, stream>>>(cnt, rowstart, blocksum, Nn);
    scan_blocks<<<1, 64, 0, stream>>>(blocksum, blockoff, nScanBlocks);
    add_offsets<<<(Nn + TPB - 1) / TPB, TPB, 0, stream>>>(rowstart, blockoff, cursor, Nn);
    scatter_kernel<<<(Etot + TPB - 1) / TPB, TPB, 0, stream>>>(src, dst, cursor, esrc, Etot);

    // ---- fp32 -> bf16 conversions ----
    convert3_kernel<<<(256 * 224 + 256 * 256 + 256 * 128 + TPB - 1) / TPB, TPB, 0, stream>>>(
        lin1_w, w1b, 256 * 224, lin2_w, w2b, 256 * 256, gat1_w, wg1b, 256 * 128);
    f32_to_bf16_vec<<<((Nn * 128 / 4) + TPB - 1) / TPB, TPB, 0, stream>>>(
        gfeat, gfeatb, Nn * 128 / 4);

    // ---- deep path (aliased under out1; must retire before gat1_gather) ----
    build_x_kernel<<<(B * 224 + TPB - 1) / TPB, TPB, 0, stream>>>(Xs, Xd, emb, xb, B);
    gemm_mfma<true><<<dim3((B + 127) / 128, 2), 256, 0, stream>>>(
        xb, w1b, lin1_b, bn1_g, bn1_b, bn1_m, bn1_v, d1, B, 256, 224);
    gemm_mfma<true><<<dim3((B + 127) / 128, 2), 256, 0, stream>>>(
        d1, w2b, lin2_b, bn2_g, bn2_b, bn2_m, bn2_v, d2, B, 256, 256);
    gemm_n8<<<(B * 8 + TPB - 1) / TPB, TPB, 0, stream>>>(Xd, wide_w, wide_b, wide, B, 64);
    gemm_n8_bf16<<<(B * 8 + TPB - 1) / TPB, TPB, 0, stream>>>(d2, dnn_w, dnn_b, deep, B, 256);

    // ---- GAT layer 1 ----
    gemm_mfma<false><<<dim3((Nn + 127) / 128, 2), 256, 0, stream>>>(
        gfeatb, wg1b, nullptr, nullptr, nullptr, nullptr, nullptr, feat1, Nn, 256, 128);
    attn_coef_bf16<4, 64><<<(Nn * 4 + TPB - 1) / TPB, TPB, 0, stream>>>(
        feat1, gat1_al, gat1_ar, el1, er1, Nn);
    gat1_gather<<<(Nn + 3) / 4, TPB, 0, stream>>>(
        feat1, el1, er1, rowstart, esrc, gat1_bias, out1, Nn);

    // ---- GAT layer 2 ----
    gemm_n8<<<(Nn * 8 + TPB - 1) / TPB, TPB, 0, stream>>>(out1, gat2_w, nullptr, feat2, Nn, 256);
    attn_coef_kernel<1, 8><<<(Nn + TPB - 1) / TPB, TPB, 0, stream>>>(
        feat2, gat2_al, gat2_ar, el2, er2, Nn);
    gat2_gather<<<(Nn * 8 + TPB - 1) / TPB, TPB, 0, stream>>>(
        feat2, el2, er2, rowstart, esrc, out2, Nn);

    // ---- gates + output ----
    final_kernel<<<(B + TPB - 1) / TPB, TPB, 0, stream>>>(
        wide, deep, out2, Xid, gat2_bias, g1w, g1b, g2w, g2b, g3w, g3b, goutw, goutb,
        (float*)d_out, B);
}

// Round 6
// 377.500 us; speedup vs baseline: 5.3258x; 1.1938x over previous
//
#include <hip/hip_runtime.h>

#define TPB 256
constexpr float BN_EPS = 1e-5f;

typedef __attribute__((ext_vector_type(8))) short short8;
typedef __attribute__((ext_vector_type(4))) float floatx4;

__device__ __forceinline__ float sigmoidf_(float x) { return 1.f / (1.f + __expf(-x)); }
__device__ __forceinline__ unsigned short f2bf(float f) {   // RTNE
    unsigned u = __float_as_uint(f);
    u += 0x7FFFu + ((u >> 16) & 1u);
    return (unsigned short)(u >> 16);
}
__device__ __forceinline__ float bf2f(unsigned short h) {
    return __uint_as_float((unsigned)h << 16);
}

// ---------- fp32 -> bf16 converters ----------
__global__ __launch_bounds__(TPB) void f32_to_bf16_vec(
    const float* __restrict__ in, unsigned short* __restrict__ out, int n4)
{
    int i = blockIdx.x * TPB + threadIdx.x;
    if (i >= n4) return;
    float4 v = ((const float4*)in)[i];
    ushort4 o;
    o.x = f2bf(v.x); o.y = f2bf(v.y); o.z = f2bf(v.z); o.w = f2bf(v.w);
    ((ushort4*)out)[i] = o;
}

__global__ __launch_bounds__(TPB) void convert3_kernel(
    const float* __restrict__ w1, unsigned short* __restrict__ o1, int n1,
    const float* __restrict__ w2, unsigned short* __restrict__ o2, int n2,
    const float* __restrict__ w3, unsigned short* __restrict__ o3, int n3)
{
    int i = blockIdx.x * TPB + threadIdx.x;
    if (i < n1) o1[i] = f2bf(w1[i]);
    else if (i < n1 + n2) o2[i - n1] = f2bf(w2[i - n1]);
    else if (i < n1 + n2 + n3) o3[i - n1 - n2] = f2bf(w3[i - n1 - n2]);
}

// ---------- build x = [sparse_embed (20*8) | dense (64)] : (B, 224) bf16 ----------
__global__ __launch_bounds__(TPB) void build_x_kernel(
    const int* __restrict__ Xs, const float* __restrict__ Xd,
    const float* __restrict__ emb, unsigned short* __restrict__ x, int B)
{
    int idx = blockIdx.x * TPB + threadIdx.x;
    if (idx >= B * 224) return;
    int b = idx / 224, c = idx - b * 224;
    float v;
    if (c < 160) {
        int s = c >> 3, j = c & 7;
        int e = Xs[b * 20 + s];
        v = emb[((size_t)s * 1000 + e) * 8 + j];
    } else {
        v = Xd[b * 64 + (c - 160)];
    }
    x[idx] = f2bf(v);
}

// ---------- bf16 MFMA GEMM: C(M,N)bf16 = A(M,K)bf16 @ W(N,K)bf16^T (+bias+bn+relu) ----------
// 128x128 tile, 4 waves 2x2, each wave 4x4 of mfma_f32_16x16x32_bf16 (one MFMA consumes
// the full 32-wide K tile: lane covers k=(lane>>4)*8+j). C/D: col=lane&15, row=(lane>>4)*4+reg.
template<bool BNRELU>
__global__ __launch_bounds__(256) void gemm_mfma(
    const unsigned short* __restrict__ A, const unsigned short* __restrict__ W,
    const float* __restrict__ bias,
    const float* __restrict__ g, const float* __restrict__ bb,
    const float* __restrict__ bm, const float* __restrict__ bv,
    unsigned short* __restrict__ C, int M, int N, int K)
{
    constexpr int SK = 40;   // padded LDS stride (bf16): 80B rows, 16B aligned, 2-way bank max (free)
    __shared__ unsigned short As[128 * SK];
    __shared__ unsigned short Bs[128 * SK];
    int tid = threadIdx.x;
    int wave = tid >> 6, lane = tid & 63;
    int wm = (wave & 1) * 64, wn = (wave >> 1) * 64;
    int m0 = blockIdx.x * 128, n0 = blockIdx.y * 128;
    int lrow = lane & 15, lk = (lane >> 4) * 8;
    floatx4 acc[4][4] = {};
    for (int k0 = 0; k0 < K; k0 += 32) {
#pragma unroll
        for (int i = 0; i < 2; ++i) {
            int idx = tid + i * 256;              // 0..511 -> 128 rows x 4 segs of 8 bf16
            int r = idx >> 2, seg = (idx & 3) * 8;
            uint4 av = make_uint4(0u, 0u, 0u, 0u);
            int gm = m0 + r;
            if (gm < M) av = *(const uint4*)(A + (size_t)gm * K + k0 + seg);
            *(uint4*)(As + r * SK + seg) = av;
            uint4 wv = make_uint4(0u, 0u, 0u, 0u);
            int gn = n0 + r;
            if (gn < N) wv = *(const uint4*)(W + (size_t)gn * K + k0 + seg);
            *(uint4*)(Bs + r * SK + seg) = wv;
        }
        __syncthreads();
        short8 af[4], bfr[4];
#pragma unroll
        for (int i = 0; i < 4; ++i)
            af[i] = *(const short8*)(As + (wm + i * 16 + lrow) * SK + lk);
#pragma unroll
        for (int j = 0; j < 4; ++j)
            bfr[j] = *(const short8*)(Bs + (wn + j * 16 + lrow) * SK + lk);
#pragma unroll
        for (int i = 0; i < 4; ++i)
#pragma unroll
            for (int j = 0; j < 4; ++j)
                acc[i][j] = __builtin_amdgcn_mfma_f32_16x16x32_bf16(
                    af[i], bfr[j], acc[i][j], 0, 0, 0);
        __syncthreads();
    }
    int crow = (lane >> 4) * 4, ccol = lane & 15;
#pragma unroll
    for (int j = 0; j < 4; ++j) {
        int gn = n0 + wn + j * 16 + ccol;
        float sc = 1.f, sh = 0.f;
        if (BNRELU) {
            sc = g[gn] * rsqrtf(bv[gn] + BN_EPS);
            sh = (bias[gn] - bm[gn]) * sc + bb[gn];   // t = (acc+bias-m)*sc + bb
        }
#pragma unroll
        for (int i = 0; i < 4; ++i) {
#pragma unroll
            for (int r = 0; r < 4; ++r) {
                int gm = m0 + wm + i * 16 + crow + r;
                if (gm >= M) continue;
                float t = acc[i][j][r];
                if (BNRELU) t = fmaxf(t * sc + sh, 0.f);
                C[(size_t)gm * N + gn] = f2bf(t);
            }
        }
    }
}

// ---------- C(M,8)fp32 = A(M,K)fp32 @ W(8,K)^T + bias  (wide path, K=64) ----------
__global__ __launch_bounds__(TPB) void gemm_n8(
    const float* __restrict__ A, const float* __restrict__ Wt,
    const float* __restrict__ bias, float* __restrict__ C, int M, int K)
{
    int idx = blockIdx.x * TPB + threadIdx.x;
    if (idx >= M * 8) return;
    int r = idx >> 3, j = idx & 7;
    const float4* a4 = (const float4*)(A + (size_t)r * K);
    const float4* w4 = (const float4*)(Wt + (size_t)j * K);
    float s = 0.f;
    int k4 = K >> 2;
    for (int k = 0; k < k4; ++k) {
        float4 av = a4[k], wv = w4[k];
        s += av.x * wv.x + av.y * wv.y + av.z * wv.z + av.w * wv.w;
    }
    if (bias) s += bias[j];
    C[idx] = s;
}

// ---------- deep head: C(M,8)fp32 = A(M,256)bf16 @ W(8,256)fp32^T + bias ----------
// One wave per row: coalesced 8B/lane load, 8 partial dots, 6-step butterfly reduce.
__global__ __launch_bounds__(TPB) void row_dot8_bf16(
    const unsigned short* __restrict__ A, const float* __restrict__ W,
    const float* __restrict__ bias, float* __restrict__ C, int M)
{
    int r = blockIdx.x * 4 + (threadIdx.x >> 6);
    if (r >= M) return;
    int lane = threadIdx.x & 63;
    uint2 ab = *(const uint2*)(A + (size_t)r * 256 + lane * 4);
    float a0 = bf2f((unsigned short)(ab.x & 0xFFFFu));
    float a1 = bf2f((unsigned short)(ab.x >> 16));
    float a2 = bf2f((unsigned short)(ab.y & 0xFFFFu));
    float a3 = bf2f((unsigned short)(ab.y >> 16));
    float p[8];
#pragma unroll
    for (int j = 0; j < 8; ++j) {
        float4 wv = *(const float4*)(W + j * 256 + lane * 4);
        p[j] = a0 * wv.x + a1 * wv.y + a2 * wv.z + a3 * wv.w;
    }
#pragma unroll
    for (int off = 1; off < 64; off <<= 1)
#pragma unroll
        for (int j = 0; j < 8; ++j)
            p[j] += __shfl_xor(p[j], off, 64);
    if (lane == 0) {
#pragma unroll
        for (int j = 0; j < 8; ++j)
            C[(size_t)r * 8 + j] = p[j] + bias[j];
    }
}

// ---------- per-node attention coefficients (bf16 feat): el/er (N, HN) ----------
template<int HN, int DHD>
__global__ __launch_bounds__(TPB) void attn_coef_bf16(
    const unsigned short* __restrict__ feat, const float* __restrict__ al,
    const float* __restrict__ ar, float* __restrict__ el, float* __restrict__ er, int Nn)
{
    int idx = blockIdx.x * TPB + threadIdx.x;
    if (idx >= Nn * HN) return;
    int n = idx / HN, h = idx - n * HN;
    const uint2* f4 = (const uint2*)(feat + (size_t)n * (HN * DHD) + h * DHD);
    const float4* al4 = (const float4*)(al + h * DHD);
    const float4* ar4 = (const float4*)(ar + h * DHD);
    float sl = 0.f, sr = 0.f;
#pragma unroll
    for (int d = 0; d < DHD / 4; ++d) {
        uint2 fb = f4[d];
        float f0 = bf2f((unsigned short)(fb.x & 0xFFFFu));
        float f1 = bf2f((unsigned short)(fb.x >> 16));
        float f2 = bf2f((unsigned short)(fb.y & 0xFFFFu));
        float f3 = bf2f((unsigned short)(fb.y >> 16));
        float4 lv = al4[d], rv = ar4[d];
        sl += f0 * lv.x + f1 * lv.y + f2 * lv.z + f3 * lv.w;
        sr += f0 * rv.x + f1 * rv.y + f2 * rv.z + f3 * rv.w;
    }
    el[idx] = sl; er[idx] = sr;
}

// ================= CSR build (by dst) =================
__global__ __launch_bounds__(TPB) void hist_kernel(
    const int* __restrict__ dst, int* __restrict__ cnt, int E)
{
    int i = blockIdx.x * TPB + threadIdx.x;
    if (i >= E) return;
    atomicAdd(&cnt[dst[i]], 1);
}

__global__ __launch_bounds__(256) void scan_local(
    const int* __restrict__ cnt, int* __restrict__ rowstart,
    int* __restrict__ blocksum, int Nn)
{
    __shared__ int wsum[4];
    int tid = threadIdx.x;
    int lane = tid & 63, wid = tid >> 6;
    int base = blockIdx.x * 1024 + tid * 4;
    int v0 = (base + 0 < Nn) ? cnt[base + 0] : 0;
    int v1 = (base + 1 < Nn) ? cnt[base + 1] : 0;
    int v2 = (base + 2 < Nn) ? cnt[base + 2] : 0;
    int v3 = (base + 3 < Nn) ? cnt[base + 3] : 0;
    int s1 = v0 + v1, s2 = s1 + v2, s3 = s2 + v3;
    int v = s3;
#pragma unroll
    for (int off = 1; off < 64; off <<= 1) {
        int t = __shfl_up(v, off, 64);
        if (lane >= off) v += t;
    }
    if (lane == 63) wsum[wid] = v;
    __syncthreads();
    int woff = 0;
#pragma unroll
    for (int w = 0; w < 4; ++w) woff += (w < wid) ? wsum[w] : 0;
    int excl = woff + v - s3;
    if (base + 0 < Nn) rowstart[base + 1] = excl + v0;
    if (base + 1 < Nn) rowstart[base + 2] = excl + s1;
    if (base + 2 < Nn) rowstart[base + 3] = excl + s2;
    if (base + 3 < Nn) rowstart[base + 4] = excl + s3;
    if (tid == 255) blocksum[blockIdx.x] = woff + v;
}

__global__ __launch_bounds__(64) void scan_blocks(
    const int* __restrict__ blocksum, int* __restrict__ blockoff, int nblocks)
{
    int lane = threadIdx.x;
    int v = (lane < nblocks) ? blocksum[lane] : 0;
#pragma unroll
    for (int off = 1; off < 64; off <<= 1) {
        int t = __shfl_up(v, off, 64);
        if (lane >= off) v += t;
    }
    if (lane < nblocks) blockoff[lane] = v - blocksum[lane];
}

__global__ __launch_bounds__(TPB) void add_offsets(
    int* __restrict__ rowstart, const int* __restrict__ blockoff,
    int* __restrict__ cursor, int Nn)
{
    int i = blockIdx.x * TPB + threadIdx.x;
    if (i >= Nn) return;
    int v = rowstart[i + 1] + blockoff[i >> 10];
    rowstart[i + 1] = v;
    if (i + 1 < Nn) cursor[i + 1] = v;
    if (i == 0) { rowstart[0] = 0; cursor[0] = 0; }
}

__global__ __launch_bounds__(TPB) void scatter_kernel(
    const int* __restrict__ src, const int* __restrict__ dst,
    int* __restrict__ cursor, int* __restrict__ esrc, int E)
{
    int i = blockIdx.x * TPB + threadIdx.x;
    if (i >= E) return;
    int pos = atomicAdd(&cursor[dst[i]], 1);
    esrc[pos] = src[i];
}

// ========== GAT1 gather FUSED: one wave per dst node ==========
// gather+softmax+bias+ELU (row h1[n] in registers), then directly:
//   feat2[n][j] = dot(h1[n], gat2_w[j])  (j<8)  via butterfly reduction
//   el2[n] = dot(feat2[n], gat2_al), er2[n] = dot(feat2[n], gat2_ar)
// h1 is never materialized.
__global__ __launch_bounds__(TPB) void gat1_gather_fused(
    const unsigned short* __restrict__ feat, const float* __restrict__ el,
    const float* __restrict__ er, const int* __restrict__ rowstart,
    const int* __restrict__ esrc, const float* __restrict__ bias,
    const float* __restrict__ w2, const float* __restrict__ al2,
    const float* __restrict__ ar2,
    float* __restrict__ feat2, float* __restrict__ el2, float* __restrict__ er2, int Nn)
{
    int n = blockIdx.x * 4 + (threadIdx.x >> 6);
    if (n >= Nn) return;
    int lane = threadIdx.x & 63;
    int h = lane >> 4;
    int c = h * 64 + (lane & 15) * 4;   // this lane's 4 columns of the 256-wide row
    float erv = er[n * 4 + h];
    int beg = rowstart[n], end = rowstart[n + 1];
    float4 acc = make_float4(0.f, 0.f, 0.f, 0.f);
    float dsum = 0.f;
    for (int e = beg; e < end; ++e) {
        int s = esrc[e];
        float ev = el[s * 4 + h] + erv;
        ev = ev > 0.f ? ev : 0.2f * ev;
        float av = __expf(ev);
        dsum += av;
        uint2 fb = *(const uint2*)(feat + (size_t)s * 256 + c);
        acc.x += av * bf2f((unsigned short)(fb.x & 0xFFFFu));
        acc.y += av * bf2f((unsigned short)(fb.x >> 16));
        acc.z += av * bf2f((unsigned short)(fb.y & 0xFFFFu));
        acc.w += av * bf2f((unsigned short)(fb.y >> 16));
    }
    float inv = 1.f / dsum;   // self-loop guarantees dsum > 0
    float4 bv = *(const float4*)(bias + c);
    float4 o;
    o.x = acc.x * inv + bv.x; o.y = acc.y * inv + bv.y;
    o.z = acc.z * inv + bv.z; o.w = acc.w * inv + bv.w;
    o.x = o.x > 0.f ? o.x : __expf(o.x) - 1.f;
    o.y = o.y > 0.f ? o.y : __expf(o.y) - 1.f;
    o.z = o.z > 0.f ? o.z : __expf(o.z) - 1.f;
    o.w = o.w > 0.f ? o.w : __expf(o.w) - 1.f;
    // ---- fused feat2 = h1row @ w2^T ----
    float p[8];
#pragma unroll
    for (int j = 0; j < 8; ++j) {
        float4 wv = *(const float4*)(w2 + j * 256 + c);
        p[j] = o.x * wv.x + o.y * wv.y + o.z * wv.z + o.w * wv.w;
    }
#pragma unroll
    for (int off = 1; off < 64; off <<= 1)
#pragma unroll
        for (int j = 0; j < 8; ++j)
            p[j] += __shfl_xor(p[j], off, 64);
    if (lane == 0) {
        float e_l = 0.f, e_r = 0.f;
#pragma unroll
        for (int j = 0; j < 8; ++j) {
            feat2[(size_t)n * 8 + j] = p[j];
            e_l += p[j] * al2[j];
            e_r += p[j] * ar2[j];
        }
        el2[n] = e_l; er2[n] = e_r;
    }
}

// ========== GAT2 gather: 8 threads per dst node ==========
__global__ __launch_bounds__(TPB) void gat2_gather(
    const float* __restrict__ feat2, const float* __restrict__ el,
    const float* __restrict__ er, const int* __restrict__ rowstart,
    const int* __restrict__ esrc, float* __restrict__ out2, int Nn)
{
    int idx = blockIdx.x * TPB + threadIdx.x;
    if (idx >= Nn * 8) return;
    int n = idx >> 3, j = idx & 7;
    float erv = er[n];
    int beg = rowstart[n], end = rowstart[n + 1];
    float acc = 0.f, dsum = 0.f;
    for (int e = beg; e < end; ++e) {
        int s = esrc[e];
        float ev = el[s] + erv;
        ev = ev > 0.f ? ev : 0.2f * ev;
        float av = __expf(ev);
        dsum += av;
        acc += av * feat2[(size_t)s * 8 + j];
    }
    out2[idx] = acc / dsum;
}

// ---------- gates + combine + output GEMM + softmax ----------
__global__ __launch_bounds__(TPB) void final_kernel(
    const float* __restrict__ wide, const float* __restrict__ deep,
    const float* __restrict__ out2, const int* __restrict__ Xid,
    const float* __restrict__ g2bias,
    const float* __restrict__ g1w, const float* __restrict__ g1b,
    const float* __restrict__ g2w, const float* __restrict__ g2b,
    const float* __restrict__ g3w, const float* __restrict__ g3b,
    const float* __restrict__ goutw, const float* __restrict__ goutb,
    float* __restrict__ out, int B)
{
    int b = blockIdx.x * TPB + threadIdx.x;
    if (b >= B) return;
    float w8[8], d8[8], g8[8];
    {
        float4 t0 = *(const float4*)(wide + (size_t)b * 8);
        float4 t1 = *(const float4*)(wide + (size_t)b * 8 + 4);
        w8[0] = t0.x; w8[1] = t0.y; w8[2] = t0.z; w8[3] = t0.w;
        w8[4] = t1.x; w8[5] = t1.y; w8[6] = t1.z; w8[7] = t1.w;
        t0 = *(const float4*)(deep + (size_t)b * 8);
        t1 = *(const float4*)(deep + (size_t)b * 8 + 4);
        d8[0] = t0.x; d8[1] = t0.y; d8[2] = t0.z; d8[3] = t0.w;
        d8[4] = t1.x; d8[5] = t1.y; d8[6] = t1.z; d8[7] = t1.w;
    }
    int commit = Xid[b * 2 + 1];
#pragma unroll
    for (int j = 0; j < 8; ++j) g8[j] = out2[(size_t)commit * 8 + j] + g2bias[j];
    float s1 = g1b[0], s2 = g2b[0], s3 = g3b[0];
#pragma unroll
    for (int j = 0; j < 8; ++j) { s1 += w8[j] * g1w[j]; s2 += d8[j] * g2w[j]; s3 += g8[j] * g3w[j]; }
    float aw = sigmoidf_(s1), bw = sigmoidf_(s2), cw = sigmoidf_(s3);
    float inv_tot = 1.f / (aw + bw + cw);
    float an = aw * inv_tot, bn = bw * inv_tot, cn = cw * inv_tot;
    float o0 = goutb[0], o1 = goutb[1];
#pragma unroll
    for (int j = 0; j < 8; ++j) {
        float c0 = an * w8[j]; o0 += goutw[j] * c0;      o1 += goutw[24 + j] * c0;
        float c1 = bn * d8[j]; o0 += goutw[8 + j] * c1;  o1 += goutw[32 + j] * c1;
        float c2 = cn * g8[j]; o0 += goutw[16 + j] * c2; o1 += goutw[40 + j] * c2;
    }
    float mx = fmaxf(o0, o1);
    float e0 = __expf(o0 - mx), e1 = __expf(o1 - mx);
    float inv = 1.f / (e0 + e1);
    out[(size_t)b * 2] = e0 * inv;
    out[(size_t)b * 2 + 1] = e1 * inv;
}

extern "C" void kernel_launch(void* const* d_in, const int* in_sizes, int n_in,
                              void* d_out, int out_size, void* d_ws, size_t ws_size,
                              hipStream_t stream)
{
    const int*   Xid    = (const int*)d_in[0];
    const int*   Xs     = (const int*)d_in[1];
    const float* Xd     = (const float*)d_in[2];
    const float* emb    = (const float*)d_in[3];
    const float* gfeat  = (const float*)d_in[4];
    const int*   src    = (const int*)d_in[5];
    const int*   dst    = (const int*)d_in[6];
    const float* wide_w = (const float*)d_in[7];
    const float* wide_b = (const float*)d_in[8];
    const float* lin1_w = (const float*)d_in[9];
    const float* lin1_b = (const float*)d_in[10];
    const float* bn1_g  = (const float*)d_in[11];
    const float* bn1_b  = (const float*)d_in[12];
    const float* bn1_m  = (const float*)d_in[13];
    const float* bn1_v  = (const float*)d_in[14];
    const float* lin2_w = (const float*)d_in[15];
    const float* lin2_b = (const float*)d_in[16];
    const float* bn2_g  = (const float*)d_in[17];
    const float* bn2_b  = (const float*)d_in[18];
    const float* bn2_m  = (const float*)d_in[19];
    const float* bn2_v  = (const float*)d_in[20];
    const float* dnn_w  = (const float*)d_in[21];
    const float* dnn_b  = (const float*)d_in[22];
    const float* gat1_w = (const float*)d_in[23];
    const float* gat1_al = (const float*)d_in[24];
    const float* gat1_ar = (const float*)d_in[25];
    const float* gat1_bias = (const float*)d_in[26];
    const float* gat2_w = (const float*)d_in[27];
    const float* gat2_al = (const float*)d_in[28];
    const float* gat2_ar = (const float*)d_in[29];
    const float* gat2_bias = (const float*)d_in[30];
    const float* g1w = (const float*)d_in[31];
    const float* g1b = (const float*)d_in[32];
    const float* g2w = (const float*)d_in[33];
    const float* g2b = (const float*)d_in[34];
    const float* g3w = (const float*)d_in[35];
    const float* g3b = (const float*)d_in[36];
    const float* goutw = (const float*)d_in[37];
    const float* goutb = (const float*)d_in[38];

    const int B    = in_sizes[0] / 2;     // 16384
    const int Nn   = in_sizes[4] / 128;   // 50000
    const int Etot = in_sizes[5];         // 450000

    // ---- workspace layout (bytes, 256-aligned). h1/out1 no longer materialized. ----
    char* base = (char*)d_ws;
    size_t off = 0;
    auto alloc = [&](size_t bytes) -> char* {
        char* p = base + off;
        off += (bytes + 255) & ~(size_t)255;
        return p;
    };
    unsigned short* xb = (unsigned short*)alloc((size_t)B * 224 * 2);
    unsigned short* d1 = (unsigned short*)alloc((size_t)B * 256 * 2);
    unsigned short* d2 = (unsigned short*)alloc((size_t)B * 256 * 2);
    unsigned short* feat1  = (unsigned short*)alloc((size_t)Nn * 256 * 2);
    unsigned short* gfeatb = (unsigned short*)alloc((size_t)Nn * 128 * 2);
    unsigned short* w1b = (unsigned short*)alloc(256 * 224 * 2);
    unsigned short* w2b = (unsigned short*)alloc(256 * 256 * 2);
    unsigned short* wg1b = (unsigned short*)alloc(256 * 128 * 2);
    float* wide  = (float*)alloc((size_t)B * 8 * 4);
    float* deep  = (float*)alloc((size_t)B * 8 * 4);
    float* el1   = (float*)alloc((size_t)Nn * 4 * 4);
    float* er1   = (float*)alloc((size_t)Nn * 4 * 4);
    float* feat2 = (float*)alloc((size_t)Nn * 8 * 4);
    float* el2   = (float*)alloc((size_t)Nn * 4);
    float* er2   = (float*)alloc((size_t)Nn * 4);
    float* out2  = (float*)alloc((size_t)Nn * 8 * 4);
    int* rowstart = (int*)alloc((size_t)(Nn + 1) * 4);
    int* cnt      = (int*)alloc((size_t)(Nn + 1) * 4);
    int* cursor   = (int*)alloc((size_t)Nn * 4);
    int* esrc     = (int*)alloc((size_t)Etot * 4);
    int* blocksum = (int*)alloc(64 * 4);
    int* blockoff = (int*)alloc(64 * 4);

    const int nScanBlocks = (Nn + 1023) / 1024;   // 49 <= 64

    // ---- CSR build ----
    hipMemsetAsync(cnt, 0, (size_t)(Nn + 1) * sizeof(int), stream);
    hist_kernel<<<(Etot + TPB - 1) / TPB, TPB, 0, stream>>>(dst, cnt, Etot);
    scan_local<<<nScanBlocks, 256, 0, stream>>>(cnt, rowstart, blocksum, Nn);
    scan_blocks<<<1, 64, 0, stream>>>(blocksum, blockoff, nScanBlocks);
    add_offsets<<<(Nn + TPB - 1) / TPB, TPB, 0, stream>>>(rowstart, blockoff, cursor, Nn);
    scatter_kernel<<<(Etot + TPB - 1) / TPB, TPB, 0, stream>>>(src, dst, cursor, esrc, Etot);

    // ---- fp32 -> bf16 conversions ----
    convert3_kernel<<<(256 * 224 + 256 * 256 + 256 * 128 + TPB - 1) / TPB, TPB, 0, stream>>>(
        lin1_w, w1b, 256 * 224, lin2_w, w2b, 256 * 256, gat1_w, wg1b, 256 * 128);
    f32_to_bf16_vec<<<((Nn * 128 / 4) + TPB - 1) / TPB, TPB, 0, stream>>>(
        gfeat, gfeatb, Nn * 128 / 4);

    // ---- deep path ----
    build_x_kernel<<<(B * 224 + TPB - 1) / TPB, TPB, 0, stream>>>(Xs, Xd, emb, xb, B);
    gemm_mfma<true><<<dim3((B + 127) / 128, 2), 256, 0, stream>>>(
        xb, w1b, lin1_b, bn1_g, bn1_b, bn1_m, bn1_v, d1, B, 256, 224);
    gemm_mfma<true><<<dim3((B + 127) / 128, 2), 256, 0, stream>>>(
        d1, w2b, lin2_b, bn2_g, bn2_b, bn2_m, bn2_v, d2, B, 256, 256);
    gemm_n8<<<(B * 8 + TPB - 1) / TPB, TPB, 0, stream>>>(Xd, wide_w, wide_b, wide, B, 64);
    row_dot8_bf16<<<(B + 3) / 4, TPB, 0, stream>>>(d2, dnn_w, dnn_b, deep, B);

    // ---- GAT layer 1 (+fused GAT2 feature/attn-coef projection) ----
    gemm_mfma<false><<<dim3((Nn + 127) / 128, 2), 256, 0, stream>>>(
        gfeatb, wg1b, nullptr, nullptr, nullptr, nullptr, nullptr, feat1, Nn, 256, 128);
    attn_coef_bf16<4, 64><<<(Nn * 4 + TPB - 1) / TPB, TPB, 0, stream>>>(
        feat1, gat1_al, gat1_ar, el1, er1, Nn);
    gat1_gather_fused<<<(Nn + 3) / 4, TPB, 0, stream>>>(
        feat1, el1, er1, rowstart, esrc, gat1_bias,
        gat2_w, gat2_al, gat2_ar, feat2, el2, er2, Nn);

    // ---- GAT layer 2 ----
    gat2_gather<<<(Nn * 8 + TPB - 1) / TPB, TPB, 0, stream>>>(
        feat2, el2, er2, rowstart, esrc, out2, Nn);

    // ---- gates + output ----
    final_kernel<<<(B + TPB - 1) / TPB, TPB, 0, stream>>>(
        wide, deep, out2, Xid, gat2_bias, g1w, g1b, g2w, g2b, g3w, g3b, goutw, goutb,
        (float*)d_out, B);
}

// Round 7
// 355.862 us; speedup vs baseline: 5.6497x; 1.0608x over previous
//
#include <hip/hip_runtime.h>

#define TPB 256
constexpr float BN_EPS = 1e-5f;

typedef __attribute__((ext_vector_type(8))) short short8;
typedef __attribute__((ext_vector_type(4))) float floatx4;

__device__ __forceinline__ float sigmoidf_(float x) { return 1.f / (1.f + __expf(-x)); }
__device__ __forceinline__ unsigned short f2bf(float f) {   // RTNE
    unsigned u = __float_as_uint(f);
    u += 0x7FFFu + ((u >> 16) & 1u);
    return (unsigned short)(u >> 16);
}
__device__ __forceinline__ float bf2f(unsigned short h) {
    return __uint_as_float((unsigned)h << 16);
}

// ---------- fused prep: weight bf16 converts + gfeat convert + build_x ----------
__global__ __launch_bounds__(TPB) void prep_kernel(
    const float* __restrict__ w1, unsigned short* __restrict__ o1,   // 256*224
    const float* __restrict__ w2, unsigned short* __restrict__ o2,   // 256*256
    const float* __restrict__ w3, unsigned short* __restrict__ o3,   // 256*128
    const float* __restrict__ gfeat, unsigned short* __restrict__ gfeatb, int ng4,
    const int* __restrict__ Xs, const float* __restrict__ Xd,
    const float* __restrict__ emb, unsigned short* __restrict__ x, int nx, int B)
{
    const int NW = 256 * 224 + 256 * 256 + 256 * 128;
    int idx = blockIdx.x * TPB + threadIdx.x;
    if (idx < NW) {
        if (idx < 256 * 224) o1[idx] = f2bf(w1[idx]);
        else if (idx < 256 * 224 + 256 * 256) o2[idx - 256 * 224] = f2bf(w2[idx - 256 * 224]);
        else o3[idx - 256 * 224 - 256 * 256] = f2bf(w3[idx - 256 * 224 - 256 * 256]);
        return;
    }
    int i = idx - NW;
    if (i < ng4) {          // gfeat fp32 -> bf16, float4 granularity
        float4 v = ((const float4*)gfeat)[i];
        ushort4 o;
        o.x = f2bf(v.x); o.y = f2bf(v.y); o.z = f2bf(v.z); o.w = f2bf(v.w);
        ((ushort4*)gfeatb)[i] = o;
        return;
    }
    i -= ng4;
    if (i >= nx) return;    // build_x: (B,224) bf16
    int b = i / 224, c = i - b * 224;
    float v;
    if (c < 160) {
        int s = c >> 3, j = c & 7;
        int e = Xs[b * 20 + s];
        v = emb[((size_t)s * 1000 + e) * 8 + j];
    } else {
        v = Xd[b * 64 + (c - 160)];
    }
    x[i] = f2bf(v);
}

// ---------- bf16 MFMA GEMM: C(M,N)bf16 = A(M,K)bf16 @ W(N,K)bf16^T (+bias+bn+relu) ----------
// 128x128 tile, 4 waves 2x2, each wave 4x4 of mfma_f32_16x16x32_bf16 (one MFMA consumes
// the full 32-wide K tile: lane covers k=(lane>>4)*8+j). C/D: col=lane&15, row=(lane>>4)*4+reg.
template<bool BNRELU>
__global__ __launch_bounds__(256) void gemm_mfma(
    const unsigned short* __restrict__ A, const unsigned short* __restrict__ W,
    const float* __restrict__ bias,
    const float* __restrict__ g, const float* __restrict__ bb,
    const float* __restrict__ bm, const float* __restrict__ bv,
    unsigned short* __restrict__ C, int M, int N, int K)
{
    constexpr int SK = 40;   // padded LDS stride (bf16): 80B rows, 16B aligned, 2-way bank max (free)
    __shared__ unsigned short As[128 * SK];
    __shared__ unsigned short Bs[128 * SK];
    int tid = threadIdx.x;
    int wave = tid >> 6, lane = tid & 63;
    int wm = (wave & 1) * 64, wn = (wave >> 1) * 64;
    int m0 = blockIdx.x * 128, n0 = blockIdx.y * 128;
    int lrow = lane & 15, lk = (lane >> 4) * 8;
    floatx4 acc[4][4] = {};
    for (int k0 = 0; k0 < K; k0 += 32) {
#pragma unroll
        for (int i = 0; i < 2; ++i) {
            int idx = tid + i * 256;              // 0..511 -> 128 rows x 4 segs of 8 bf16
            int r = idx >> 2, seg = (idx & 3) * 8;
            uint4 av = make_uint4(0u, 0u, 0u, 0u);
            int gm = m0 + r;
            if (gm < M) av = *(const uint4*)(A + (size_t)gm * K + k0 + seg);
            *(uint4*)(As + r * SK + seg) = av;
            uint4 wv = make_uint4(0u, 0u, 0u, 0u);
            int gn = n0 + r;
            if (gn < N) wv = *(const uint4*)(W + (size_t)gn * K + k0 + seg);
            *(uint4*)(Bs + r * SK + seg) = wv;
        }
        __syncthreads();
        short8 af[4], bfr[4];
#pragma unroll
        for (int i = 0; i < 4; ++i)
            af[i] = *(const short8*)(As + (wm + i * 16 + lrow) * SK + lk);
#pragma unroll
        for (int j = 0; j < 4; ++j)
            bfr[j] = *(const short8*)(Bs + (wn + j * 16 + lrow) * SK + lk);
#pragma unroll
        for (int i = 0; i < 4; ++i)
#pragma unroll
            for (int j = 0; j < 4; ++j)
                acc[i][j] = __builtin_amdgcn_mfma_f32_16x16x32_bf16(
                    af[i], bfr[j], acc[i][j], 0, 0, 0);
        __syncthreads();
    }
    int crow = (lane >> 4) * 4, ccol = lane & 15;
#pragma unroll
    for (int j = 0; j < 4; ++j) {
        int gn = n0 + wn + j * 16 + ccol;
        float sc = 1.f, sh = 0.f;
        if (BNRELU) {
            sc = g[gn] * rsqrtf(bv[gn] + BN_EPS);
            sh = (bias[gn] - bm[gn]) * sc + bb[gn];   // t = (acc+bias-m)*sc + bb
        }
#pragma unroll
        for (int i = 0; i < 4; ++i) {
#pragma unroll
            for (int r = 0; r < 4; ++r) {
                int gm = m0 + wm + i * 16 + crow + r;
                if (gm >= M) continue;
                float t = acc[i][j][r];
                if (BNRELU) t = fmaxf(t * sc + sh, 0.f);
                C[(size_t)gm * N + gn] = f2bf(t);
            }
        }
    }
}

// ---------- wide head: C(M,8) = Xd(M,64) @ W(8,64)^T + bias; wave per row ----------
__global__ __launch_bounds__(TPB) void wide_row_kernel(
    const float* __restrict__ Xd, const float* __restrict__ W,
    const float* __restrict__ bias, float* __restrict__ C, int M)
{
    int r = blockIdx.x * 4 + (threadIdx.x >> 6);
    if (r >= M) return;
    int lane = threadIdx.x & 63;
    float a = Xd[(size_t)r * 64 + lane];
    float p[8];
#pragma unroll
    for (int j = 0; j < 8; ++j) p[j] = a * W[j * 64 + lane];
#pragma unroll
    for (int off = 1; off < 64; off <<= 1)
#pragma unroll
        for (int j = 0; j < 8; ++j)
            p[j] += __shfl_xor(p[j], off, 64);
    if (lane == 0) {
#pragma unroll
        for (int j = 0; j < 8; ++j)
            C[(size_t)r * 8 + j] = p[j] + bias[j];
    }
}

// ---------- deep head: C(M,8)fp32 = A(M,256)bf16 @ W(8,256)fp32^T + bias ----------
__global__ __launch_bounds__(TPB) void row_dot8_bf16(
    const unsigned short* __restrict__ A, const float* __restrict__ W,
    const float* __restrict__ bias, float* __restrict__ C, int M)
{
    int r = blockIdx.x * 4 + (threadIdx.x >> 6);
    if (r >= M) return;
    int lane = threadIdx.x & 63;
    uint2 ab = *(const uint2*)(A + (size_t)r * 256 + lane * 4);
    float a0 = bf2f((unsigned short)(ab.x & 0xFFFFu));
    float a1 = bf2f((unsigned short)(ab.x >> 16));
    float a2 = bf2f((unsigned short)(ab.y & 0xFFFFu));
    float a3 = bf2f((unsigned short)(ab.y >> 16));
    float p[8];
#pragma unroll
    for (int j = 0; j < 8; ++j) {
        float4 wv = *(const float4*)(W + j * 256 + lane * 4);
        p[j] = a0 * wv.x + a1 * wv.y + a2 * wv.z + a3 * wv.w;
    }
#pragma unroll
    for (int off = 1; off < 64; off <<= 1)
#pragma unroll
        for (int j = 0; j < 8; ++j)
            p[j] += __shfl_xor(p[j], off, 64);
    if (lane == 0) {
#pragma unroll
        for (int j = 0; j < 8; ++j)
            C[(size_t)r * 8 + j] = p[j] + bias[j];
    }
}

// ---------- per-node attention coefficients (bf16 feat): el/er (N, 4) ----------
template<int HN, int DHD>
__global__ __launch_bounds__(TPB) void attn_coef_bf16(
    const unsigned short* __restrict__ feat, const float* __restrict__ al,
    const float* __restrict__ ar, float* __restrict__ el, float* __restrict__ er, int Nn)
{
    int idx = blockIdx.x * TPB + threadIdx.x;
    if (idx >= Nn * HN) return;
    int n = idx / HN, h = idx - n * HN;
    const uint2* f4 = (const uint2*)(feat + (size_t)n * (HN * DHD) + h * DHD);
    const float4* al4 = (const float4*)(al + h * DHD);
    const float4* ar4 = (const float4*)(ar + h * DHD);
    float sl = 0.f, sr = 0.f;
#pragma unroll
    for (int d = 0; d < DHD / 4; ++d) {
        uint2 fb = f4[d];
        float f0 = bf2f((unsigned short)(fb.x & 0xFFFFu));
        float f1 = bf2f((unsigned short)(fb.x >> 16));
        float f2 = bf2f((unsigned short)(fb.y & 0xFFFFu));
        float f3 = bf2f((unsigned short)(fb.y >> 16));
        float4 lv = al4[d], rv = ar4[d];
        sl += f0 * lv.x + f1 * lv.y + f2 * lv.z + f3 * lv.w;
        sr += f0 * rv.x + f1 * rv.y + f2 * rv.z + f3 * rv.w;
    }
    el[idx] = sl; er[idx] = sr;
}

// ================= CSR build (by dst) =================
__global__ __launch_bounds__(TPB) void hist_kernel(
    const int* __restrict__ dst, int* __restrict__ cnt, int E)
{
    int i = blockIdx.x * TPB + threadIdx.x;
    if (i >= E) return;
    atomicAdd(&cnt[dst[i]], 1);
}

__global__ __launch_bounds__(256) void scan_local(
    const int* __restrict__ cnt, int* __restrict__ rowstart,
    int* __restrict__ blocksum, int Nn)
{
    __shared__ int wsum[4];
    int tid = threadIdx.x;
    int lane = tid & 63, wid = tid >> 6;
    int base = blockIdx.x * 1024 + tid * 4;
    int v0 = (base + 0 < Nn) ? cnt[base + 0] : 0;
    int v1 = (base + 1 < Nn) ? cnt[base + 1] : 0;
    int v2 = (base + 2 < Nn) ? cnt[base + 2] : 0;
    int v3 = (base + 3 < Nn) ? cnt[base + 3] : 0;
    int s1 = v0 + v1, s2 = s1 + v2, s3 = s2 + v3;
    int v = s3;
#pragma unroll
    for (int off = 1; off < 64; off <<= 1) {
        int t = __shfl_up(v, off, 64);
        if (lane >= off) v += t;
    }
    if (lane == 63) wsum[wid] = v;
    __syncthreads();
    int woff = 0;
#pragma unroll
    for (int w = 0; w < 4; ++w) woff += (w < wid) ? wsum[w] : 0;
    int excl = woff + v - s3;
    if (base + 0 < Nn) rowstart[base + 1] = excl + v0;
    if (base + 1 < Nn) rowstart[base + 2] = excl + s1;
    if (base + 2 < Nn) rowstart[base + 3] = excl + s2;
    if (base + 3 < Nn) rowstart[base + 4] = excl + s3;
    if (tid == 255) blocksum[blockIdx.x] = woff + v;
}

__global__ __launch_bounds__(64) void scan_blocks(
    const int* __restrict__ blocksum, int* __restrict__ blockoff, int nblocks)
{
    int lane = threadIdx.x;
    int v = (lane < nblocks) ? blocksum[lane] : 0;
#pragma unroll
    for (int off = 1; off < 64; off <<= 1) {
        int t = __shfl_up(v, off, 64);
        if (lane >= off) v += t;
    }
    if (lane < nblocks) blockoff[lane] = v - blocksum[lane];
}

__global__ __launch_bounds__(TPB) void add_offsets(
    int* __restrict__ rowstart, const int* __restrict__ blockoff,
    int* __restrict__ cursor, int Nn)
{
    int i = blockIdx.x * TPB + threadIdx.x;
    if (i >= Nn) return;
    int v = rowstart[i + 1] + blockoff[i >> 10];
    rowstart[i + 1] = v;
    if (i + 1 < Nn) cursor[i + 1] = v;
    if (i == 0) { rowstart[0] = 0; cursor[0] = 0; }
}

__global__ __launch_bounds__(TPB) void scatter_kernel(
    const int* __restrict__ src, const int* __restrict__ dst,
    int* __restrict__ cursor, int* __restrict__ esrc, int E)
{
    int i = blockIdx.x * TPB + threadIdx.x;
    if (i >= E) return;
    int pos = atomicAdd(&cursor[dst[i]], 1);
    esrc[pos] = src[i];
}

// ========== GAT1 gather FUSED + 4x unrolled: one wave per dst node ==========
// gather+softmax+bias+ELU in registers, then feat2 = h1row @ w2^T (butterfly) and el2/er2.
// 4x edge unroll: 4 esrc, then 4 el + 4 feat loads in flight before any consume.
// Accumulation order over edges preserved (bit-identical to serial loop).
__global__ __launch_bounds__(TPB) void gat1_gather_fused(
    const unsigned short* __restrict__ feat, const float* __restrict__ el,
    const float* __restrict__ er, const int* __restrict__ rowstart,
    const int* __restrict__ esrc, const float* __restrict__ bias,
    const float* __restrict__ w2, const float* __restrict__ al2,
    const float* __restrict__ ar2,
    float* __restrict__ feat2, float* __restrict__ el2, float* __restrict__ er2, int Nn)
{
    int n = blockIdx.x * 4 + (threadIdx.x >> 6);
    if (n >= Nn) return;
    int lane = threadIdx.x & 63;
    int h = lane >> 4;
    int c = h * 64 + (lane & 15) * 4;   // this lane's 4 columns of the 256-wide row
    float erv = er[n * 4 + h];
    int beg = rowstart[n], end = rowstart[n + 1];
    float4 acc = make_float4(0.f, 0.f, 0.f, 0.f);
    float dsum = 0.f;
    int e = beg;
    for (; e + 4 <= end; e += 4) {
        int sv[4]; float lv[4]; uint2 fb[4];
#pragma unroll
        for (int u = 0; u < 4; ++u) sv[u] = esrc[e + u];
#pragma unroll
        for (int u = 0; u < 4; ++u) lv[u] = el[sv[u] * 4 + h];
#pragma unroll
        for (int u = 0; u < 4; ++u) fb[u] = *(const uint2*)(feat + (size_t)sv[u] * 256 + c);
#pragma unroll
        for (int u = 0; u < 4; ++u) {
            float ev = lv[u] + erv;
            ev = ev > 0.f ? ev : 0.2f * ev;
            float av = __expf(ev);
            dsum += av;
            acc.x += av * bf2f((unsigned short)(fb[u].x & 0xFFFFu));
            acc.y += av * bf2f((unsigned short)(fb[u].x >> 16));
            acc.z += av * bf2f((unsigned short)(fb[u].y & 0xFFFFu));
            acc.w += av * bf2f((unsigned short)(fb[u].y >> 16));
        }
    }
    for (; e < end; ++e) {
        int s = esrc[e];
        float ev = el[s * 4 + h] + erv;
        ev = ev > 0.f ? ev : 0.2f * ev;
        float av = __expf(ev);
        dsum += av;
        uint2 fb = *(const uint2*)(feat + (size_t)s * 256 + c);
        acc.x += av * bf2f((unsigned short)(fb.x & 0xFFFFu));
        acc.y += av * bf2f((unsigned short)(fb.x >> 16));
        acc.z += av * bf2f((unsigned short)(fb.y & 0xFFFFu));
        acc.w += av * bf2f((unsigned short)(fb.y >> 16));
    }
    float inv = 1.f / dsum;   // self-loop guarantees dsum > 0
    float4 bv = *(const float4*)(bias + c);
    float4 o;
    o.x = acc.x * inv + bv.x; o.y = acc.y * inv + bv.y;
    o.z = acc.z * inv + bv.z; o.w = acc.w * inv + bv.w;
    o.x = o.x > 0.f ? o.x : __expf(o.x) - 1.f;
    o.y = o.y > 0.f ? o.y : __expf(o.y) - 1.f;
    o.z = o.z > 0.f ? o.z : __expf(o.z) - 1.f;
    o.w = o.w > 0.f ? o.w : __expf(o.w) - 1.f;
    // ---- fused feat2 = h1row @ w2^T ----
    float p[8];
#pragma unroll
    for (int j = 0; j < 8; ++j) {
        float4 wv = *(const float4*)(w2 + j * 256 + c);
        p[j] = o.x * wv.x + o.y * wv.y + o.z * wv.z + o.w * wv.w;
    }
#pragma unroll
    for (int off = 1; off < 64; off <<= 1)
#pragma unroll
        for (int j = 0; j < 8; ++j)
            p[j] += __shfl_xor(p[j], off, 64);
    if (lane == 0) {
        float e_l = 0.f, e_r = 0.f;
#pragma unroll
        for (int j = 0; j < 8; ++j) {
            feat2[(size_t)n * 8 + j] = p[j];
            e_l += p[j] * al2[j];
            e_r += p[j] * ar2[j];
        }
        el2[n] = e_l; er2[n] = e_r;
    }
}

// ========== GAT2 gather, 4x unrolled: 8 threads per dst node ==========
__global__ __launch_bounds__(TPB) void gat2_gather(
    const float* __restrict__ feat2, const float* __restrict__ el,
    const float* __restrict__ er, const int* __restrict__ rowstart,
    const int* __restrict__ esrc, float* __restrict__ out2, int Nn)
{
    int idx = blockIdx.x * TPB + threadIdx.x;
    if (idx >= Nn * 8) return;
    int n = idx >> 3, j = idx & 7;
    float erv = er[n];
    int beg = rowstart[n], end = rowstart[n + 1];
    float acc = 0.f, dsum = 0.f;
    int e = beg;
    for (; e + 4 <= end; e += 4) {
        int sv[4]; float lv[4], fv[4];
#pragma unroll
        for (int u = 0; u < 4; ++u) sv[u] = esrc[e + u];
#pragma unroll
        for (int u = 0; u < 4; ++u) lv[u] = el[sv[u]];
#pragma unroll
        for (int u = 0; u < 4; ++u) fv[u] = feat2[(size_t)sv[u] * 8 + j];
#pragma unroll
        for (int u = 0; u < 4; ++u) {
            float ev = lv[u] + erv;
            ev = ev > 0.f ? ev : 0.2f * ev;
            float av = __expf(ev);
            dsum += av;
            acc += av * fv[u];
        }
    }
    for (; e < end; ++e) {
        int s = esrc[e];
        float ev = el[s] + erv;
        ev = ev > 0.f ? ev : 0.2f * ev;
        float av = __expf(ev);
        dsum += av;
        acc += av * feat2[(size_t)s * 8 + j];
    }
    out2[idx] = acc / dsum;
}

// ---------- gates + combine + output GEMM + softmax ----------
__global__ __launch_bounds__(TPB) void final_kernel(
    const float* __restrict__ wide, const float* __restrict__ deep,
    const float* __restrict__ out2, const int* __restrict__ Xid,
    const float* __restrict__ g2bias,
    const float* __restrict__ g1w, const float* __restrict__ g1b,
    const float* __restrict__ g2w, const float* __restrict__ g2b,
    const float* __restrict__ g3w, const float* __restrict__ g3b,
    const float* __restrict__ goutw, const float* __restrict__ goutb,
    float* __restrict__ out, int B)
{
    int b = blockIdx.x * TPB + threadIdx.x;
    if (b >= B) return;
    float w8[8], d8[8], g8[8];
    {
        float4 t0 = *(const float4*)(wide + (size_t)b * 8);
        float4 t1 = *(const float4*)(wide + (size_t)b * 8 + 4);
        w8[0] = t0.x; w8[1] = t0.y; w8[2] = t0.z; w8[3] = t0.w;
        w8[4] = t1.x; w8[5] = t1.y; w8[6] = t1.z; w8[7] = t1.w;
        t0 = *(const float4*)(deep + (size_t)b * 8);
        t1 = *(const float4*)(deep + (size_t)b * 8 + 4);
        d8[0] = t0.x; d8[1] = t0.y; d8[2] = t0.z; d8[3] = t0.w;
        d8[4] = t1.x; d8[5] = t1.y; d8[6] = t1.z; d8[7] = t1.w;
    }
    int commit = Xid[b * 2 + 1];
#pragma unroll
    for (int j = 0; j < 8; ++j) g8[j] = out2[(size_t)commit * 8 + j] + g2bias[j];
    float s1 = g1b[0], s2 = g2b[0], s3 = g3b[0];
#pragma unroll
    for (int j = 0; j < 8; ++j) { s1 += w8[j] * g1w[j]; s2 += d8[j] * g2w[j]; s3 += g8[j] * g3w[j]; }
    float aw = sigmoidf_(s1), bw = sigmoidf_(s2), cw = sigmoidf_(s3);
    float inv_tot = 1.f / (aw + bw + cw);
    float an = aw * inv_tot, bn = bw * inv_tot, cn = cw * inv_tot;
    float o0 = goutb[0], o1 = goutb[1];
#pragma unroll
    for (int j = 0; j < 8; ++j) {
        float c0 = an * w8[j]; o0 += goutw[j] * c0;      o1 += goutw[24 + j] * c0;
        float c1 = bn * d8[j]; o0 += goutw[8 + j] * c1;  o1 += goutw[32 + j] * c1;
        float c2 = cn * g8[j]; o0 += goutw[16 + j] * c2; o1 += goutw[40 + j] * c2;
    }
    float mx = fmaxf(o0, o1);
    float e0 = __expf(o0 - mx), e1 = __expf(o1 - mx);
    float inv = 1.f / (e0 + e1);
    out[(size_t)b * 2] = e0 * inv;
    out[(size_t)b * 2 + 1] = e1 * inv;
}

extern "C" void kernel_launch(void* const* d_in, const int* in_sizes, int n_in,
                              void* d_out, int out_size, void* d_ws, size_t ws_size,
                              hipStream_t stream)
{
    const int*   Xid    = (const int*)d_in[0];
    const int*   Xs     = (const int*)d_in[1];
    const float* Xd     = (const float*)d_in[2];
    const float* emb    = (const float*)d_in[3];
    const float* gfeat  = (const float*)d_in[4];
    const int*   src    = (const int*)d_in[5];
    const int*   dst    = (const int*)d_in[6];
    const float* wide_w = (const float*)d_in[7];
    const float* wide_b = (const float*)d_in[8];
    const float* lin1_w = (const float*)d_in[9];
    const float* lin1_b = (const float*)d_in[10];
    const float* bn1_g  = (const float*)d_in[11];
    const float* bn1_b  = (const float*)d_in[12];
    const float* bn1_m  = (const float*)d_in[13];
    const float* bn1_v  = (const float*)d_in[14];
    const float* lin2_w = (const float*)d_in[15];
    const float* lin2_b = (const float*)d_in[16];
    const float* bn2_g  = (const float*)d_in[17];
    const float* bn2_b  = (const float*)d_in[18];
    const float* bn2_m  = (const float*)d_in[19];
    const float* bn2_v  = (const float*)d_in[20];
    const float* dnn_w  = (const float*)d_in[21];
    const float* dnn_b  = (const float*)d_in[22];
    const float* gat1_w = (const float*)d_in[23];
    const float* gat1_al = (const float*)d_in[24];
    const float* gat1_ar = (const float*)d_in[25];
    const float* gat1_bias = (const float*)d_in[26];
    const float* gat2_w = (const float*)d_in[27];
    const float* gat2_al = (const float*)d_in[28];
    const float* gat2_ar = (const float*)d_in[29];
    const float* gat2_bias = (const float*)d_in[30];
    const float* g1w = (const float*)d_in[31];
    const float* g1b = (const float*)d_in[32];
    const float* g2w = (const float*)d_in[33];
    const float* g2b = (const float*)d_in[34];
    const float* g3w = (const float*)d_in[35];
    const float* g3b = (const float*)d_in[36];
    const float* goutw = (const float*)d_in[37];
    const float* goutb = (const float*)d_in[38];

    const int B    = in_sizes[0] / 2;     // 16384
    const int Nn   = in_sizes[4] / 128;   // 50000
    const int Etot = in_sizes[5];         // 450000

    // ---- workspace layout (bytes, 256-aligned) ----
    char* base = (char*)d_ws;
    size_t off = 0;
    auto alloc = [&](size_t bytes) -> char* {
        char* p = base + off;
        off += (bytes + 255) & ~(size_t)255;
        return p;
    };
    unsigned short* xb = (unsigned short*)alloc((size_t)B * 224 * 2);
    unsigned short* d1 = (unsigned short*)alloc((size_t)B * 256 * 2);
    unsigned short* d2 = (unsigned short*)alloc((size_t)B * 256 * 2);
    unsigned short* feat1  = (unsigned short*)alloc((size_t)Nn * 256 * 2);
    unsigned short* gfeatb = (unsigned short*)alloc((size_t)Nn * 128 * 2);
    unsigned short* w1b = (unsigned short*)alloc(256 * 224 * 2);
    unsigned short* w2b = (unsigned short*)alloc(256 * 256 * 2);
    unsigned short* wg1b = (unsigned short*)alloc(256 * 128 * 2);
    float* wide  = (float*)alloc((size_t)B * 8 * 4);
    float* deep  = (float*)alloc((size_t)B * 8 * 4);
    float* el1   = (float*)alloc((size_t)Nn * 4 * 4);
    float* er1   = (float*)alloc((size_t)Nn * 4 * 4);
    float* feat2 = (float*)alloc((size_t)Nn * 8 * 4);
    float* el2   = (float*)alloc((size_t)Nn * 4);
    float* er2   = (float*)alloc((size_t)Nn * 4);
    float* out2  = (float*)alloc((size_t)Nn * 8 * 4);
    int* rowstart = (int*)alloc((size_t)(Nn + 1) * 4);
    int* cnt      = (int*)alloc((size_t)(Nn + 1) * 4);
    int* cursor   = (int*)alloc((size_t)Nn * 4);
    int* esrc     = (int*)alloc((size_t)Etot * 4);
    int* blocksum = (int*)alloc(64 * 4);
    int* blockoff = (int*)alloc(64 * 4);

    const int nScanBlocks = (Nn + 1023) / 1024;   // 49 <= 64

    // ---- CSR build ----
    hipMemsetAsync(cnt, 0, (size_t)(Nn + 1) * sizeof(int), stream);
    hist_kernel<<<(Etot + TPB - 1) / TPB, TPB, 0, stream>>>(dst, cnt, Etot);
    scan_local<<<nScanBlocks, 256, 0, stream>>>(cnt, rowstart, blocksum, Nn);
    scan_blocks<<<1, 64, 0, stream>>>(blocksum, blockoff, nScanBlocks);
    add_offsets<<<(Nn + TPB - 1) / TPB, TPB, 0, stream>>>(rowstart, blockoff, cursor, Nn);
    scatter_kernel<<<(Etot + TPB - 1) / TPB, TPB, 0, stream>>>(src, dst, cursor, esrc, Etot);

    // ---- fused prep: weight converts + gfeat convert + build_x ----
    {
        const int NW = 256 * 224 + 256 * 256 + 256 * 128;
        const int NG4 = Nn * 128 / 4;
        const int NX = B * 224;
        int total = NW + NG4 + NX;
        prep_kernel<<<(total + TPB - 1) / TPB, TPB, 0, stream>>>(
            lin1_w, w1b, lin2_w, w2b, gat1_w, wg1b,
            gfeat, gfeatb, NG4, Xs, Xd, emb, xb, NX, B);
    }

    // ---- deep path ----
    gemm_mfma<true><<<dim3((B + 127) / 128, 2), 256, 0, stream>>>(
        xb, w1b, lin1_b, bn1_g, bn1_b, bn1_m, bn1_v, d1, B, 256, 224);
    gemm_mfma<true><<<dim3((B + 127) / 128, 2), 256, 0, stream>>>(
        d1, w2b, lin2_b, bn2_g, bn2_b, bn2_m, bn2_v, d2, B, 256, 256);
    wide_row_kernel<<<(B + 3) / 4, TPB, 0, stream>>>(Xd, wide_w, wide_b, wide, B);
    row_dot8_bf16<<<(B + 3) / 4, TPB, 0, stream>>>(d2, dnn_w, dnn_b, deep, B);

    // ---- GAT layer 1 (+fused GAT2 feature/attn-coef projection) ----
    gemm_mfma<false><<<dim3((Nn + 127) / 128, 2), 256, 0, stream>>>(
        gfeatb, wg1b, nullptr, nullptr, nullptr, nullptr, nullptr, feat1, Nn, 256, 128);
    attn_coef_bf16<4, 64><<<(Nn * 4 + TPB - 1) / TPB, TPB, 0, stream>>>(
        feat1, gat1_al, gat1_ar, el1, er1, Nn);
    gat1_gather_fused<<<(Nn + 3) / 4, TPB, 0, stream>>>(
        feat1, el1, er1, rowstart, esrc, gat1_bias,
        gat2_w, gat2_al, gat2_ar, feat2, el2, er2, Nn);

    // ---- GAT layer 2 ----
    gat2_gather<<<(Nn * 8 + TPB - 1) / TPB, TPB, 0, stream>>>(
        feat2, el2, er2, rowstart, esrc, out2, Nn);

    // ---- gates + output ----
    final_kernel<<<(B + TPB - 1) / TPB, TPB, 0, stream>>>(
        wide, deep, out2, Xid, gat2_bias, g1w, g1b, g2w, g2b, g3w, g3b, goutw, goutb,
        (float*)d_out, B);
}

// Round 8
// 338.692 us; speedup vs baseline: 5.9361x; 1.0507x over previous
//
#include <hip/hip_runtime.h>

#define TPB 256
constexpr float BN_EPS = 1e-5f;

typedef __attribute__((ext_vector_type(8))) short short8;
typedef __attribute__((ext_vector_type(4))) float floatx4;

__device__ __forceinline__ float sigmoidf_(float x) { return 1.f / (1.f + __expf(-x)); }
__device__ __forceinline__ unsigned short f2bf(float f) {   // RTNE
    unsigned u = __float_as_uint(f);
    u += 0x7FFFu + ((u >> 16) & 1u);
    return (unsigned short)(u >> 16);
}
__device__ __forceinline__ float bf2f(unsigned short h) {
    return __uint_as_float((unsigned)h << 16);
}

// ---------- fused prep: weight bf16 converts + gfeat convert + build_x ----------
__global__ __launch_bounds__(TPB) void prep_kernel(
    const float* __restrict__ w1, unsigned short* __restrict__ o1,   // 256*224
    const float* __restrict__ w2, unsigned short* __restrict__ o2,   // 256*256
    const float* __restrict__ w3, unsigned short* __restrict__ o3,   // 256*128
    const float* __restrict__ gfeat, unsigned short* __restrict__ gfeatb, int ng4,
    const int* __restrict__ Xs, const float* __restrict__ Xd,
    const float* __restrict__ emb, unsigned short* __restrict__ x, int nx, int B)
{
    const int NW = 256 * 224 + 256 * 256 + 256 * 128;
    int idx = blockIdx.x * TPB + threadIdx.x;
    if (idx < NW) {
        if (idx < 256 * 224) o1[idx] = f2bf(w1[idx]);
        else if (idx < 256 * 224 + 256 * 256) o2[idx - 256 * 224] = f2bf(w2[idx - 256 * 224]);
        else o3[idx - 256 * 224 - 256 * 256] = f2bf(w3[idx - 256 * 224 - 256 * 256]);
        return;
    }
    int i = idx - NW;
    if (i < ng4) {          // gfeat fp32 -> bf16, float4 granularity
        float4 v = ((const float4*)gfeat)[i];
        ushort4 o;
        o.x = f2bf(v.x); o.y = f2bf(v.y); o.z = f2bf(v.z); o.w = f2bf(v.w);
        ((ushort4*)gfeatb)[i] = o;
        return;
    }
    i -= ng4;
    if (i >= nx) return;    // build_x: (B,224) bf16
    int b = i / 224, c = i - b * 224;
    float v;
    if (c < 160) {
        int s = c >> 3, j = c & 7;
        int e = Xs[b * 20 + s];
        v = emb[((size_t)s * 1000 + e) * 8 + j];
    } else {
        v = Xd[b * 64 + (c - 160)];
    }
    x[i] = f2bf(v);
}

// ---------- bf16 MFMA GEMM: C(M,N)bf16 = A(M,K)bf16 @ W(N,K)bf16^T (+bias+bn+relu) ----------
// 64x64 tile (4 waves 2x2, each wave 2x2 of mfma_f32_16x16x32_bf16) for occupancy:
// small-M GEMMs need many blocks (lin1: 1024 blocks = 4/CU vs 1/CU at 128-tile).
// One MFMA consumes the full 32-wide K tile (lane covers k=(lane>>4)*8+j).
// C/D: col=lane&15, row=(lane>>4)*4+reg.
template<bool BNRELU>
__global__ __launch_bounds__(256) void gemm_mfma(
    const unsigned short* __restrict__ A, const unsigned short* __restrict__ W,
    const float* __restrict__ bias,
    const float* __restrict__ g, const float* __restrict__ bb,
    const float* __restrict__ bm, const float* __restrict__ bv,
    unsigned short* __restrict__ C, int M, int N, int K)
{
    constexpr int SK = 40;   // padded LDS stride (bf16): 80B rows, 16B aligned, 2-way bank max (free)
    __shared__ unsigned short As[64 * SK];
    __shared__ unsigned short Bs[64 * SK];
    int tid = threadIdx.x;
    int wave = tid >> 6, lane = tid & 63;
    int wm = (wave & 1) * 32, wn = (wave >> 1) * 32;
    int m0 = blockIdx.x * 64, n0 = blockIdx.y * 64;
    int lrow = lane & 15, lk = (lane >> 4) * 8;
    floatx4 acc[2][2] = {};
    for (int k0 = 0; k0 < K; k0 += 32) {
        {
            int r = tid >> 2, seg = (tid & 3) * 8;   // 64 rows x 4 segs of 8 bf16
            uint4 av = make_uint4(0u, 0u, 0u, 0u);
            int gm = m0 + r;
            if (gm < M) av = *(const uint4*)(A + (size_t)gm * K + k0 + seg);
            *(uint4*)(As + r * SK + seg) = av;
            uint4 wv = make_uint4(0u, 0u, 0u, 0u);
            int gn = n0 + r;
            if (gn < N) wv = *(const uint4*)(W + (size_t)gn * K + k0 + seg);
            *(uint4*)(Bs + r * SK + seg) = wv;
        }
        __syncthreads();
        short8 af[2], bfr[2];
#pragma unroll
        for (int i = 0; i < 2; ++i)
            af[i] = *(const short8*)(As + (wm + i * 16 + lrow) * SK + lk);
#pragma unroll
        for (int j = 0; j < 2; ++j)
            bfr[j] = *(const short8*)(Bs + (wn + j * 16 + lrow) * SK + lk);
#pragma unroll
        for (int i = 0; i < 2; ++i)
#pragma unroll
            for (int j = 0; j < 2; ++j)
                acc[i][j] = __builtin_amdgcn_mfma_f32_16x16x32_bf16(
                    af[i], bfr[j], acc[i][j], 0, 0, 0);
        __syncthreads();
    }
    int crow = (lane >> 4) * 4, ccol = lane & 15;
#pragma unroll
    for (int j = 0; j < 2; ++j) {
        int gn = n0 + wn + j * 16 + ccol;
        float sc = 1.f, sh = 0.f;
        if (BNRELU) {
            sc = g[gn] * rsqrtf(bv[gn] + BN_EPS);
            sh = (bias[gn] - bm[gn]) * sc + bb[gn];   // t = (acc+bias-m)*sc + bb
        }
#pragma unroll
        for (int i = 0; i < 2; ++i) {
#pragma unroll
            for (int r = 0; r < 2 * 2; ++r) {
                int gm = m0 + wm + i * 16 + crow + r;
                if (gm >= M) continue;
                float t = acc[i][j][r];
                if (BNRELU) t = fmaxf(t * sc + sh, 0.f);
                C[(size_t)gm * N + gn] = f2bf(t);
            }
        }
    }
}

// ---------- merged heads: wide (Xd@wide_w^T) and deep (d2@dnn_w^T), wave per row ----------
__global__ __launch_bounds__(TPB) void heads_kernel(
    const float* __restrict__ Xd, const float* __restrict__ Ww,
    const float* __restrict__ wb, float* __restrict__ wide,
    const unsigned short* __restrict__ d2, const float* __restrict__ Wd,
    const float* __restrict__ db, float* __restrict__ deep, int B)
{
    int nb = (B + 3) / 4;
    int lane = threadIdx.x & 63;
    float p[8];
    if ((int)blockIdx.x < nb) {                 // wide: K=64
        int r = blockIdx.x * 4 + (threadIdx.x >> 6);
        if (r >= B) return;
        float a = Xd[(size_t)r * 64 + lane];
#pragma unroll
        for (int j = 0; j < 8; ++j) p[j] = a * Ww[j * 64 + lane];
#pragma unroll
        for (int off = 1; off < 64; off <<= 1)
#pragma unroll
            for (int j = 0; j < 8; ++j) p[j] += __shfl_xor(p[j], off, 64);
        if (lane == 0) {
#pragma unroll
            for (int j = 0; j < 8; ++j) wide[(size_t)r * 8 + j] = p[j] + wb[j];
        }
    } else {                                    // deep: K=256 bf16
        int r = (blockIdx.x - nb) * 4 + (threadIdx.x >> 6);
        if (r >= B) return;
        uint2 ab = *(const uint2*)(d2 + (size_t)r * 256 + lane * 4);
        float a0 = bf2f((unsigned short)(ab.x & 0xFFFFu));
        float a1 = bf2f((unsigned short)(ab.x >> 16));
        float a2 = bf2f((unsigned short)(ab.y & 0xFFFFu));
        float a3 = bf2f((unsigned short)(ab.y >> 16));
#pragma unroll
        for (int j = 0; j < 8; ++j) {
            float4 wv = *(const float4*)(Wd + j * 256 + lane * 4);
            p[j] = a0 * wv.x + a1 * wv.y + a2 * wv.z + a3 * wv.w;
        }
#pragma unroll
        for (int off = 1; off < 64; off <<= 1)
#pragma unroll
            for (int j = 0; j < 8; ++j) p[j] += __shfl_xor(p[j], off, 64);
        if (lane == 0) {
#pragma unroll
            for (int j = 0; j < 8; ++j) deep[(size_t)r * 8 + j] = p[j] + db[j];
        }
    }
}

// ---------- per-node attention coefficients (bf16 feat): el/er (N, 4) ----------
template<int HN, int DHD>
__global__ __launch_bounds__(TPB) void attn_coef_bf16(
    const unsigned short* __restrict__ feat, const float* __restrict__ al,
    const float* __restrict__ ar, float* __restrict__ el, float* __restrict__ er, int Nn)
{
    int idx = blockIdx.x * TPB + threadIdx.x;
    if (idx >= Nn * HN) return;
    int n = idx / HN, h = idx - n * HN;
    const uint2* f4 = (const uint2*)(feat + (size_t)n * (HN * DHD) + h * DHD);
    const float4* al4 = (const float4*)(al + h * DHD);
    const float4* ar4 = (const float4*)(ar + h * DHD);
    float sl = 0.f, sr = 0.f;
#pragma unroll
    for (int d = 0; d < DHD / 4; ++d) {
        uint2 fb = f4[d];
        float f0 = bf2f((unsigned short)(fb.x & 0xFFFFu));
        float f1 = bf2f((unsigned short)(fb.x >> 16));
        float f2 = bf2f((unsigned short)(fb.y & 0xFFFFu));
        float f3 = bf2f((unsigned short)(fb.y >> 16));
        float4 lv = al4[d], rv = ar4[d];
        sl += f0 * lv.x + f1 * lv.y + f2 * lv.z + f3 * lv.w;
        sr += f0 * rv.x + f1 * rv.y + f2 * rv.z + f3 * rv.w;
    }
    el[idx] = sl; er[idx] = sr;
}

// ================= CSR build (by dst) =================
__global__ __launch_bounds__(TPB) void hist_kernel(
    const int* __restrict__ dst, int* __restrict__ cnt, int E)
{
    int i = blockIdx.x * TPB + threadIdx.x;
    if (i >= E) return;
    atomicAdd(&cnt[dst[i]], 1);
}

__global__ __launch_bounds__(256) void scan_local(
    const int* __restrict__ cnt, int* __restrict__ rowstart,
    int* __restrict__ blocksum, int Nn)
{
    __shared__ int wsum[4];
    int tid = threadIdx.x;
    int lane = tid & 63, wid = tid >> 6;
    int base = blockIdx.x * 1024 + tid * 4;
    int v0 = (base + 0 < Nn) ? cnt[base + 0] : 0;
    int v1 = (base + 1 < Nn) ? cnt[base + 1] : 0;
    int v2 = (base + 2 < Nn) ? cnt[base + 2] : 0;
    int v3 = (base + 3 < Nn) ? cnt[base + 3] : 0;
    int s1 = v0 + v1, s2 = s1 + v2, s3 = s2 + v3;
    int v = s3;
#pragma unroll
    for (int off = 1; off < 64; off <<= 1) {
        int t = __shfl_up(v, off, 64);
        if (lane >= off) v += t;
    }
    if (lane == 63) wsum[wid] = v;
    __syncthreads();
    int woff = 0;
#pragma unroll
    for (int w = 0; w < 4; ++w) woff += (w < wid) ? wsum[w] : 0;
    int excl = woff + v - s3;
    if (base + 0 < Nn) rowstart[base + 1] = excl + v0;
    if (base + 1 < Nn) rowstart[base + 2] = excl + s1;
    if (base + 2 < Nn) rowstart[base + 3] = excl + s2;
    if (base + 3 < Nn) rowstart[base + 4] = excl + s3;
    if (tid == 255) blocksum[blockIdx.x] = woff + v;
}

__global__ __launch_bounds__(64) void scan_blocks(
    const int* __restrict__ blocksum, int* __restrict__ blockoff, int nblocks)
{
    int lane = threadIdx.x;
    int v = (lane < nblocks) ? blocksum[lane] : 0;
#pragma unroll
    for (int off = 1; off < 64; off <<= 1) {
        int t = __shfl_up(v, off, 64);
        if (lane >= off) v += t;
    }
    if (lane < nblocks) blockoff[lane] = v - blocksum[lane];
}

__global__ __launch_bounds__(TPB) void add_offsets(
    int* __restrict__ rowstart, const int* __restrict__ blockoff,
    int* __restrict__ cursor, int Nn)
{
    int i = blockIdx.x * TPB + threadIdx.x;
    if (i >= Nn) return;
    int v = rowstart[i + 1] + blockoff[i >> 10];
    rowstart[i + 1] = v;
    if (i + 1 < Nn) cursor[i + 1] = v;
    if (i == 0) { rowstart[0] = 0; cursor[0] = 0; }
}

__global__ __launch_bounds__(TPB) void scatter_kernel(
    const int* __restrict__ src, const int* __restrict__ dst,
    int* __restrict__ cursor, int* __restrict__ esrc, int E)
{
    int i = blockIdx.x * TPB + threadIdx.x;
    if (i >= E) return;
    int pos = atomicAdd(&cursor[dst[i]], 1);
    esrc[pos] = src[i];
}

// ========== GAT1 gather FUSED + 4x unrolled: one wave per dst node ==========
__global__ __launch_bounds__(TPB) void gat1_gather_fused(
    const unsigned short* __restrict__ feat, const float* __restrict__ el,
    const float* __restrict__ er, const int* __restrict__ rowstart,
    const int* __restrict__ esrc, const float* __restrict__ bias,
    const float* __restrict__ w2, const float* __restrict__ al2,
    const float* __restrict__ ar2,
    float* __restrict__ feat2, float* __restrict__ el2, float* __restrict__ er2, int Nn)
{
    int n = blockIdx.x * 4 + (threadIdx.x >> 6);
    if (n >= Nn) return;
    int lane = threadIdx.x & 63;
    int h = lane >> 4;
    int c = h * 64 + (lane & 15) * 4;   // this lane's 4 columns of the 256-wide row
    float erv = er[n * 4 + h];
    int beg = rowstart[n], end = rowstart[n + 1];
    float4 acc = make_float4(0.f, 0.f, 0.f, 0.f);
    float dsum = 0.f;
    int e = beg;
    for (; e + 4 <= end; e += 4) {
        int sv[4]; float lv[4]; uint2 fb[4];
#pragma unroll
        for (int u = 0; u < 4; ++u) sv[u] = esrc[e + u];
#pragma unroll
        for (int u = 0; u < 4; ++u) lv[u] = el[sv[u] * 4 + h];
#pragma unroll
        for (int u = 0; u < 4; ++u) fb[u] = *(const uint2*)(feat + (size_t)sv[u] * 256 + c);
#pragma unroll
        for (int u = 0; u < 4; ++u) {
            float ev = lv[u] + erv;
            ev = ev > 0.f ? ev : 0.2f * ev;
            float av = __expf(ev);
            dsum += av;
            acc.x += av * bf2f((unsigned short)(fb[u].x & 0xFFFFu));
            acc.y += av * bf2f((unsigned short)(fb[u].x >> 16));
            acc.z += av * bf2f((unsigned short)(fb[u].y & 0xFFFFu));
            acc.w += av * bf2f((unsigned short)(fb[u].y >> 16));
        }
    }
    for (; e < end; ++e) {
        int s = esrc[e];
        float ev = el[s * 4 + h] + erv;
        ev = ev > 0.f ? ev : 0.2f * ev;
        float av = __expf(ev);
        dsum += av;
        uint2 fb = *(const uint2*)(feat + (size_t)s * 256 + c);
        acc.x += av * bf2f((unsigned short)(fb.x & 0xFFFFu));
        acc.y += av * bf2f((unsigned short)(fb.x >> 16));
        acc.z += av * bf2f((unsigned short)(fb.y & 0xFFFFu));
        acc.w += av * bf2f((unsigned short)(fb.y >> 16));
    }
    float inv = 1.f / dsum;   // self-loop guarantees dsum > 0
    float4 bv = *(const float4*)(bias + c);
    float4 o;
    o.x = acc.x * inv + bv.x; o.y = acc.y * inv + bv.y;
    o.z = acc.z * inv + bv.z; o.w = acc.w * inv + bv.w;
    o.x = o.x > 0.f ? o.x : __expf(o.x) - 1.f;
    o.y = o.y > 0.f ? o.y : __expf(o.y) - 1.f;
    o.z = o.z > 0.f ? o.z : __expf(o.z) - 1.f;
    o.w = o.w > 0.f ? o.w : __expf(o.w) - 1.f;
    // ---- fused feat2 = h1row @ w2^T ----
    float p[8];
#pragma unroll
    for (int j = 0; j < 8; ++j) {
        float4 wv = *(const float4*)(w2 + j * 256 + c);
        p[j] = o.x * wv.x + o.y * wv.y + o.z * wv.z + o.w * wv.w;
    }
#pragma unroll
    for (int off = 1; off < 64; off <<= 1)
#pragma unroll
        for (int j = 0; j < 8; ++j)
            p[j] += __shfl_xor(p[j], off, 64);
    if (lane == 0) {
        float e_l = 0.f, e_r = 0.f;
#pragma unroll
        for (int j = 0; j < 8; ++j) {
            feat2[(size_t)n * 8 + j] = p[j];
            e_l += p[j] * al2[j];
            e_r += p[j] * ar2[j];
        }
        el2[n] = e_l; er2[n] = e_r;
    }
}

// ========== GAT2 gather keyed by batch row (only commit nodes needed), 4x unrolled ==========
__global__ __launch_bounds__(TPB) void gat2_gather_b(
    const float* __restrict__ feat2, const float* __restrict__ el,
    const float* __restrict__ er, const int* __restrict__ rowstart,
    const int* __restrict__ esrc, const int* __restrict__ Xid,
    float* __restrict__ gcn, int B)
{
    int idx = blockIdx.x * TPB + threadIdx.x;
    if (idx >= B * 8) return;
    int b = idx >> 3, j = idx & 7;
    int n = Xid[b * 2 + 1];
    float erv = er[n];
    int beg = rowstart[n], end = rowstart[n + 1];
    float acc = 0.f, dsum = 0.f;
    int e = beg;
    for (; e + 4 <= end; e += 4) {
        int sv[4]; float lv[4], fv[4];
#pragma unroll
        for (int u = 0; u < 4; ++u) sv[u] = esrc[e + u];
#pragma unroll
        for (int u = 0; u < 4; ++u) lv[u] = el[sv[u]];
#pragma unroll
        for (int u = 0; u < 4; ++u) fv[u] = feat2[(size_t)sv[u] * 8 + j];
#pragma unroll
        for (int u = 0; u < 4; ++u) {
            float ev = lv[u] + erv;
            ev = ev > 0.f ? ev : 0.2f * ev;
            float av = __expf(ev);
            dsum += av;
            acc += av * fv[u];
        }
    }
    for (; e < end; ++e) {
        int s = esrc[e];
        float ev = el[s] + erv;
        ev = ev > 0.f ? ev : 0.2f * ev;
        float av = __expf(ev);
        dsum += av;
        acc += av * feat2[(size_t)s * 8 + j];
    }
    gcn[idx] = acc / dsum;
}

// ---------- gates + combine + output GEMM + softmax ----------
__global__ __launch_bounds__(TPB) void final_kernel(
    const float* __restrict__ wide, const float* __restrict__ deep,
    const float* __restrict__ gcn,
    const float* __restrict__ g2bias,
    const float* __restrict__ g1w, const float* __restrict__ g1b,
    const float* __restrict__ g2w, const float* __restrict__ g2b,
    const float* __restrict__ g3w, const float* __restrict__ g3b,
    const float* __restrict__ goutw, const float* __restrict__ goutb,
    float* __restrict__ out, int B)
{
    int b = blockIdx.x * TPB + threadIdx.x;
    if (b >= B) return;
    float w8[8], d8[8], g8[8];
    {
        float4 t0 = *(const float4*)(wide + (size_t)b * 8);
        float4 t1 = *(const float4*)(wide + (size_t)b * 8 + 4);
        w8[0] = t0.x; w8[1] = t0.y; w8[2] = t0.z; w8[3] = t0.w;
        w8[4] = t1.x; w8[5] = t1.y; w8[6] = t1.z; w8[7] = t1.w;
        t0 = *(const float4*)(deep + (size_t)b * 8);
        t1 = *(const float4*)(deep + (size_t)b * 8 + 4);
        d8[0] = t0.x; d8[1] = t0.y; d8[2] = t0.z; d8[3] = t0.w;
        d8[4] = t1.x; d8[5] = t1.y; d8[6] = t1.z; d8[7] = t1.w;
        t0 = *(const float4*)(gcn + (size_t)b * 8);
        t1 = *(const float4*)(gcn + (size_t)b * 8 + 4);
        g8[0] = t0.x; g8[1] = t0.y; g8[2] = t0.z; g8[3] = t0.w;
        g8[4] = t1.x; g8[5] = t1.y; g8[6] = t1.z; g8[7] = t1.w;
    }
#pragma unroll
    for (int j = 0; j < 8; ++j) g8[j] += g2bias[j];
    float s1 = g1b[0], s2 = g2b[0], s3 = g3b[0];
#pragma unroll
    for (int j = 0; j < 8; ++j) { s1 += w8[j] * g1w[j]; s2 += d8[j] * g2w[j]; s3 += g8[j] * g3w[j]; }
    float aw = sigmoidf_(s1), bw = sigmoidf_(s2), cw = sigmoidf_(s3);
    float inv_tot = 1.f / (aw + bw + cw);
    float an = aw * inv_tot, bn = bw * inv_tot, cn = cw * inv_tot;
    float o0 = goutb[0], o1 = goutb[1];
#pragma unroll
    for (int j = 0; j < 8; ++j) {
        float c0 = an * w8[j]; o0 += goutw[j] * c0;      o1 += goutw[24 + j] * c0;
        float c1 = bn * d8[j]; o0 += goutw[8 + j] * c1;  o1 += goutw[32 + j] * c1;
        float c2 = cn * g8[j]; o0 += goutw[16 + j] * c2; o1 += goutw[40 + j] * c2;
    }
    float mx = fmaxf(o0, o1);
    float e0 = __expf(o0 - mx), e1 = __expf(o1 - mx);
    float inv = 1.f / (e0 + e1);
    out[(size_t)b * 2] = e0 * inv;
    out[(size_t)b * 2 + 1] = e1 * inv;
}

extern "C" void kernel_launch(void* const* d_in, const int* in_sizes, int n_in,
                              void* d_out, int out_size, void* d_ws, size_t ws_size,
                              hipStream_t stream)
{
    const int*   Xid    = (const int*)d_in[0];
    const int*   Xs     = (const int*)d_in[1];
    const float* Xd     = (const float*)d_in[2];
    const float* emb    = (const float*)d_in[3];
    const float* gfeat  = (const float*)d_in[4];
    const int*   src    = (const int*)d_in[5];
    const int*   dst    = (const int*)d_in[6];
    const float* wide_w = (const float*)d_in[7];
    const float* wide_b = (const float*)d_in[8];
    const float* lin1_w = (const float*)d_in[9];
    const float* lin1_b = (const float*)d_in[10];
    const float* bn1_g  = (const float*)d_in[11];
    const float* bn1_b  = (const float*)d_in[12];
    const float* bn1_m  = (const float*)d_in[13];
    const float* bn1_v  = (const float*)d_in[14];
    const float* lin2_w = (const float*)d_in[15];
    const float* lin2_b = (const float*)d_in[16];
    const float* bn2_g  = (const float*)d_in[17];
    const float* bn2_b  = (const float*)d_in[18];
    const float* bn2_m  = (const float*)d_in[19];
    const float* bn2_v  = (const float*)d_in[20];
    const float* dnn_w  = (const float*)d_in[21];
    const float* dnn_b  = (const float*)d_in[22];
    const float* gat1_w = (const float*)d_in[23];
    const float* gat1_al = (const float*)d_in[24];
    const float* gat1_ar = (const float*)d_in[25];
    const float* gat1_bias = (const float*)d_in[26];
    const float* gat2_w = (const float*)d_in[27];
    const float* gat2_al = (const float*)d_in[28];
    const float* gat2_ar = (const float*)d_in[29];
    const float* gat2_bias = (const float*)d_in[30];
    const float* g1w = (const float*)d_in[31];
    const float* g1b = (const float*)d_in[32];
    const float* g2w = (const float*)d_in[33];
    const float* g2b = (const float*)d_in[34];
    const float* g3w = (const float*)d_in[35];
    const float* g3b = (const float*)d_in[36];
    const float* goutw = (const float*)d_in[37];
    const float* goutb = (const float*)d_in[38];

    const int B    = in_sizes[0] / 2;     // 16384
    const int Nn   = in_sizes[4] / 128;   // 50000
    const int Etot = in_sizes[5];         // 450000

    // ---- workspace layout (bytes, 256-aligned) ----
    char* base = (char*)d_ws;
    size_t off = 0;
    auto alloc = [&](size_t bytes) -> char* {
        char* p = base + off;
        off += (bytes + 255) & ~(size_t)255;
        return p;
    };
    unsigned short* xb = (unsigned short*)alloc((size_t)B * 224 * 2);
    unsigned short* d1 = (unsigned short*)alloc((size_t)B * 256 * 2);
    unsigned short* d2 = (unsigned short*)alloc((size_t)B * 256 * 2);
    unsigned short* feat1  = (unsigned short*)alloc((size_t)Nn * 256 * 2);
    unsigned short* gfeatb = (unsigned short*)alloc((size_t)Nn * 128 * 2);
    unsigned short* w1b = (unsigned short*)alloc(256 * 224 * 2);
    unsigned short* w2b = (unsigned short*)alloc(256 * 256 * 2);
    unsigned short* wg1b = (unsigned short*)alloc(256 * 128 * 2);
    float* wide  = (float*)alloc((size_t)B * 8 * 4);
    float* deep  = (float*)alloc((size_t)B * 8 * 4);
    float* el1   = (float*)alloc((size_t)Nn * 4 * 4);
    float* er1   = (float*)alloc((size_t)Nn * 4 * 4);
    float* feat2 = (float*)alloc((size_t)Nn * 8 * 4);
    float* el2   = (float*)alloc((size_t)Nn * 4);
    float* er2   = (float*)alloc((size_t)Nn * 4);
    float* gcn   = (float*)alloc((size_t)B * 8 * 4);
    int* rowstart = (int*)alloc((size_t)(Nn + 1) * 4);
    int* cnt      = (int*)alloc((size_t)(Nn + 1) * 4);
    int* cursor   = (int*)alloc((size_t)Nn * 4);
    int* esrc     = (int*)alloc((size_t)Etot * 4);
    int* blocksum = (int*)alloc(64 * 4);
    int* blockoff = (int*)alloc(64 * 4);

    const int nScanBlocks = (Nn + 1023) / 1024;   // 49 <= 64

    // ---- CSR build ----
    hipMemsetAsync(cnt, 0, (size_t)(Nn + 1) * sizeof(int), stream);
    hist_kernel<<<(Etot + TPB - 1) / TPB, TPB, 0, stream>>>(dst, cnt, Etot);
    scan_local<<<nScanBlocks, 256, 0, stream>>>(cnt, rowstart, blocksum, Nn);
    scan_blocks<<<1, 64, 0, stream>>>(blocksum, blockoff, nScanBlocks);
    add_offsets<<<(Nn + TPB - 1) / TPB, TPB, 0, stream>>>(rowstart, blockoff, cursor, Nn);
    scatter_kernel<<<(Etot + TPB - 1) / TPB, TPB, 0, stream>>>(src, dst, cursor, esrc, Etot);

    // ---- fused prep: weight converts + gfeat convert + build_x ----
    {
        const int NW = 256 * 224 + 256 * 256 + 256 * 128;
        const int NG4 = Nn * 128 / 4;
        const int NX = B * 224;
        int total = NW + NG4 + NX;
        prep_kernel<<<(total + TPB - 1) / TPB, TPB, 0, stream>>>(
            lin1_w, w1b, lin2_w, w2b, gat1_w, wg1b,
            gfeat, gfeatb, NG4, Xs, Xd, emb, xb, NX, B);
    }

    // ---- deep path ----
    gemm_mfma<true><<<dim3((B + 63) / 64, 4), 256, 0, stream>>>(
        xb, w1b, lin1_b, bn1_g, bn1_b, bn1_m, bn1_v, d1, B, 256, 224);
    gemm_mfma<true><<<dim3((B + 63) / 64, 4), 256, 0, stream>>>(
        d1, w2b, lin2_b, bn2_g, bn2_b, bn2_m, bn2_v, d2, B, 256, 256);
    heads_kernel<<<2 * ((B + 3) / 4), TPB, 0, stream>>>(
        Xd, wide_w, wide_b, wide, d2, dnn_w, dnn_b, deep, B);

    // ---- GAT layer 1 (+fused GAT2 feature/attn-coef projection) ----
    gemm_mfma<false><<<dim3((Nn + 63) / 64, 4), 256, 0, stream>>>(
        gfeatb, wg1b, nullptr, nullptr, nullptr, nullptr, nullptr, feat1, Nn, 256, 128);
    attn_coef_bf16<4, 64><<<(Nn * 4 + TPB - 1) / TPB, TPB, 0, stream>>>(
        feat1, gat1_al, gat1_ar, el1, er1, Nn);
    gat1_gather_fused<<<(Nn + 3) / 4, TPB, 0, stream>>>(
        feat1, el1, er1, rowstart, esrc, gat1_bias,
        gat2_w, gat2_al, gat2_ar, feat2, el2, er2, Nn);

    // ---- GAT layer 2 (only commit nodes, keyed by batch row) ----
    gat2_gather_b<<<(B * 8 + TPB - 1) / TPB, TPB, 0, stream>>>(
        feat2, el2, er2, rowstart, esrc, Xid, gcn, B);

    // ---- gates + output ----
    final_kernel<<<(B + TPB - 1) / TPB, TPB, 0, stream>>>(
        wide, deep, gcn, gat2_bias, g1w, g1b, g2w, g2b, g3w, g3b, goutw, goutb,
        (float*)d_out, B);
}